// Round 1
// baseline (411.663 us; speedup 1.0000x reference)
//
#include <hip/hip_runtime.h>
#include <stdint.h>

#define H 16
#define DH 64
#define T 2048
#define SS 2048
#define L 4096
#define DIM 1024
#define BB 2

typedef __bf16 bf16x8 __attribute__((ext_vector_type(8)));
typedef float f32x4 __attribute__((ext_vector_type(4)));

__device__ __forceinline__ unsigned short f2bf(float f){
  unsigned u = __builtin_bit_cast(unsigned, f);
  u += 0x7fff + ((u >> 16) & 1);
  return (unsigned short)(u >> 16);
}

__device__ __forceinline__ void gload_lds16(const void* g, void* l){
  void* gnc = const_cast<void*>(g);
  __builtin_amdgcn_global_load_lds((__attribute__((address_space(1))) void*)gnc,
                                   (__attribute__((address_space(3))) void*)l, 16, 0, 0);
}

// ---------------- LayerNorm (x rows then ctx rows) -> bf16 ----------------
__global__ __launch_bounds__(256) void ln_kernel(const float* __restrict__ x, const float* __restrict__ ctx,
                          const float* __restrict__ g, const float* __restrict__ b,
                          unsigned short* __restrict__ out){
  int row = blockIdx.x;
  int tid = threadIdx.x;
  const float* src = (row < BB*T) ? (x + (size_t)row*DIM) : (ctx + (size_t)(row - BB*T)*DIM);
  float4 v = reinterpret_cast<const float4*>(src)[tid];
  float s  = v.x + v.y + v.z + v.w;
  float s2 = v.x*v.x + v.y*v.y + v.z*v.z + v.w*v.w;
  #pragma unroll
  for (int off = 32; off > 0; off >>= 1){
    s  += __shfl_down(s,  off, 64);
    s2 += __shfl_down(s2, off, 64);
  }
  __shared__ float red[8];
  if ((tid & 63) == 0){ red[(tid>>6)*2] = s; red[(tid>>6)*2+1] = s2; }
  __syncthreads();
  s  = red[0] + red[2] + red[4] + red[6];
  s2 = red[1] + red[3] + red[5] + red[7];
  float mean = s * (1.0f/DIM);
  float var  = s2 * (1.0f/DIM) - mean*mean;
  float rstd = rsqrtf(var + 1e-5f);
  float4 gg = reinterpret_cast<const float4*>(g)[tid];
  float4 bv = reinterpret_cast<const float4*>(b)[tid];
  ushort4 o;
  o.x = f2bf((v.x-mean)*rstd*gg.x + bv.x);
  o.y = f2bf((v.y-mean)*rstd*gg.y + bv.y);
  o.z = f2bf((v.z-mean)*rstd*gg.z + bv.z);
  o.w = f2bf((v.w-mean)*rstd*gg.w + bv.w);
  reinterpret_cast<ushort4*>(out + (size_t)row*DIM)[tid] = o;
}

// ---------------- transpose fp32 [R][C] -> bf16 [C][R] ----------------
__global__ __launch_bounds__(256) void transpose_f32_bf16(const float* __restrict__ in,
                          unsigned short* __restrict__ out, int R, int C){
  __shared__ float tile[32][33];
  int c0 = blockIdx.x*32, r0 = blockIdx.y*32;
  int tx = threadIdx.x, ty = threadIdx.y;
  #pragma unroll
  for (int k = 0; k < 4; k++)
    tile[ty + k*8][tx] = in[(size_t)(r0 + ty + k*8)*C + c0 + tx];
  __syncthreads();
  #pragma unroll
  for (int k = 0; k < 4; k++)
    out[(size_t)(c0 + ty + k*8)*R + r0 + tx] = f2bf(tile[tx][ty + k*8]);
}

// ---------------- QKV GEMM: [8192 x 1024] @ [1024 x 3072], scatter epilogue ----------------
__global__ __launch_bounds__(256) void qkv_gemm(const unsigned short* __restrict__ A,
      const unsigned short* __restrict__ Bt, const float* __restrict__ bias,
      unsigned short* __restrict__ qbuf, unsigned short* __restrict__ kbuf,
      unsigned short* __restrict__ vtbuf){
  int n0 = blockIdx.x*128, m0 = blockIdx.y*128;
  if (m0 >= BB*T && n0 < DIM) return;   // ctx rows need no Q columns
  __shared__ unsigned short at[128*32];
  __shared__ unsigned short btile[128*32];
  int tid = threadIdx.x, lane = tid & 63, wv = tid >> 6;
  int wm = (wv >> 1)*64, wn = (wv & 1)*64;
  f32x4 acc[4][4];
  #pragma unroll
  for (int i = 0; i < 4; i++)
    #pragma unroll
    for (int j = 0; j < 4; j++) acc[i][j] = (f32x4){0.f,0.f,0.f,0.f};

  for (int k0 = 0; k0 < DIM; k0 += 32){
    #pragma unroll
    for (int c = 0; c < 2; c++){
      int idx = c*256 + tid;
      int row = idx >> 2, koff = (idx & 3)*16;
      gload_lds16((const char*)A  + ((size_t)(m0+row)*DIM + k0)*2 + koff,
                  (char*)at + (c*256 + wv*64)*16);
      gload_lds16((const char*)Bt + ((size_t)(n0+row)*DIM + k0)*2 + koff,
                  (char*)btile + (c*256 + wv*64)*16);
    }
    __syncthreads();
    bf16x8 af[4], bfv[4];
    #pragma unroll
    for (int i = 0; i < 4; i++){
      af[i]  = *reinterpret_cast<const bf16x8*>((const char*)at    + (wm + i*16 + (lane&15))*64 + (lane>>4)*16);
      bfv[i] = *reinterpret_cast<const bf16x8*>((const char*)btile + (wn + i*16 + (lane&15))*64 + (lane>>4)*16);
    }
    #pragma unroll
    for (int mi = 0; mi < 4; mi++)
      #pragma unroll
      for (int ni = 0; ni < 4; ni++)
        acc[mi][ni] = __builtin_amdgcn_mfma_f32_16x16x32_bf16(af[mi], bfv[ni], acc[mi][ni], 0,0,0);
    __syncthreads();
  }

  #pragma unroll
  for (int ni = 0; ni < 4; ni++){
    int gn = n0 + wn + ni*16 + (lane & 15);
    float bv = bias[gn];
    int sec = gn >> 10, cc = gn & 1023, hh = cc >> 6, d = cc & 63;
    #pragma unroll
    for (int mi = 0; mi < 4; mi++){
      int gmb = m0 + wm + mi*16 + ((lane >> 4) << 2);
      bool isctx = gmb >= BB*T;
      int rm = isctx ? gmb - BB*T : gmb;
      int bidx = rm >> 11, tt = rm & 2047;
      size_t bh = (size_t)bidx*H + hh;
      if (sec == 0){
        if (isctx) continue;
        #pragma unroll
        for (int r = 0; r < 4; r++)
          qbuf[(bh*T + tt + r)*DH + d] = f2bf((acc[mi][ni][r] + bv)*0.125f);
      } else if (sec == 1){
        int j = isctx ? T + tt : tt;
        #pragma unroll
        for (int r = 0; r < 4; r++)
          kbuf[(bh*L + j + r)*DH + d] = f2bf(acc[mi][ni][r] + bv);
      } else {
        int j = isctx ? T + tt : tt;
        ushort4 o;
        o.x = f2bf(acc[mi][ni][0] + bv);
        o.y = f2bf(acc[mi][ni][1] + bv);
        o.z = f2bf(acc[mi][ni][2] + bv);
        o.w = f2bf(acc[mi][ni][3] + bv);
        *reinterpret_cast<ushort4*>(vtbuf + (bh*DH + d)*L + j) = o;
      }
    }
  }
}

// ---------------- flash attention: Q[B,H,T,64] x K[B,H,L,64], Vt[B,H,64,L] ----------------
__global__ __launch_bounds__(256) void attn_kernel(const unsigned short* __restrict__ q,
      const unsigned short* __restrict__ kbuf, const unsigned short* __restrict__ vtbuf,
      unsigned short* __restrict__ ao){
  int qt = blockIdx.x, hh = blockIdx.y, b = blockIdx.z;
  int tid = threadIdx.x, lane = tid & 63, wv = tid >> 6;
  __shared__ unsigned short kt[64*64];
  __shared__ unsigned short vtt[64*64];
  __shared__ unsigned short pbuf[4][16*64];
  size_t bh = (size_t)b*H + hh;
  int qrow = qt*64 + wv*16 + (lane & 15);
  const unsigned short* qp = q + (bh*T + qrow)*DH;
  bf16x8 qf0 = *reinterpret_cast<const bf16x8*>(qp + (lane>>4)*8);
  bf16x8 qf1 = *reinterpret_cast<const bf16x8*>(qp + 32 + (lane>>4)*8);
  float m_r[4], l_r[4];
  f32x4 o_acc[4];
  #pragma unroll
  for (int r = 0; r < 4; r++){ m_r[r] = -1e30f; l_r[r] = 0.f; }
  #pragma unroll
  for (int nd = 0; nd < 4; nd++) o_acc[nd] = (f32x4){0.f,0.f,0.f,0.f};
  const char* kg = (const char*)(kbuf + bh*(size_t)L*DH);
  const char* vg = (const char*)(vtbuf + bh*(size_t)DH*L);

  for (int jt = 0; jt < L/64; ++jt){
    #pragma unroll
    for (int c = 0; c < 2; c++){
      int idx = c*256 + tid;
      gload_lds16(kg + (size_t)jt*8192 + idx*16, (char*)kt + (c*256 + wv*64)*16);
      int d = idx >> 3, s0 = (idx & 7)*8;
      gload_lds16(vg + (size_t)d*(L*2) + (size_t)(jt*64 + s0)*2, (char*)vtt + (c*256 + wv*64)*16);
    }
    __syncthreads();

    f32x4 sc[4];
    #pragma unroll
    for (int ni = 0; ni < 4; ni++){
      sc[ni] = (f32x4){0.f,0.f,0.f,0.f};
      bf16x8 kf0 = *reinterpret_cast<const bf16x8*>((const char*)kt + (ni*16 + (lane&15))*128 + (lane>>4)*16);
      bf16x8 kf1 = *reinterpret_cast<const bf16x8*>((const char*)kt + (ni*16 + (lane&15))*128 + 64 + (lane>>4)*16);
      sc[ni] = __builtin_amdgcn_mfma_f32_16x16x32_bf16(qf0, kf0, sc[ni], 0,0,0);
      sc[ni] = __builtin_amdgcn_mfma_f32_16x16x32_bf16(qf1, kf1, sc[ni], 0,0,0);
    }
    float tmax[4] = {-1e30f,-1e30f,-1e30f,-1e30f};
    #pragma unroll
    for (int ni = 0; ni < 4; ni++)
      #pragma unroll
      for (int r = 0; r < 4; r++) tmax[r] = fmaxf(tmax[r], sc[ni][r]);
    #pragma unroll
    for (int r = 0; r < 4; r++)
      for (int st = 1; st < 16; st <<= 1) tmax[r] = fmaxf(tmax[r], __shfl_xor(tmax[r], st, 64));
    float alpha[4], psum[4];
    #pragma unroll
    for (int r = 0; r < 4; r++){
      float mn = fmaxf(m_r[r], tmax[r]);
      alpha[r] = __expf(m_r[r] - mn);
      m_r[r] = mn; psum[r] = 0.f;
    }
    #pragma unroll
    for (int ni = 0; ni < 4; ni++)
      #pragma unroll
      for (int r = 0; r < 4; r++){
        float p = __expf(sc[ni][r] - m_r[r]);
        sc[ni][r] = p; psum[r] += p;
      }
    #pragma unroll
    for (int r = 0; r < 4; r++){
      for (int st = 1; st < 16; st <<= 1) psum[r] += __shfl_xor(psum[r], st, 64);
      l_r[r] = l_r[r]*alpha[r] + psum[r];
    }
    #pragma unroll
    for (int nd = 0; nd < 4; nd++)
      #pragma unroll
      for (int r = 0; r < 4; r++) o_acc[nd][r] *= alpha[r];
    // P (D-layout) -> LDS -> A-layout fragments; wave-private buffer, DS in-order per wave
    #pragma unroll
    for (int ni = 0; ni < 4; ni++)
      #pragma unroll
      for (int r = 0; r < 4; r++)
        pbuf[wv][(((lane>>4)<<2) + r)*64 + ni*16 + (lane&15)] = f2bf(sc[ni][r]);
    asm volatile("" ::: "memory");
    #pragma unroll
    for (int kk = 0; kk < 2; kk++){
      bf16x8 pf = *reinterpret_cast<const bf16x8*>((const char*)pbuf[wv] + (lane&15)*128 + kk*64 + (lane>>4)*16);
      #pragma unroll
      for (int nd = 0; nd < 4; nd++){
        bf16x8 vf = *reinterpret_cast<const bf16x8*>((const char*)vtt + (nd*16 + (lane&15))*128 + kk*64 + (lane>>4)*16);
        o_acc[nd] = __builtin_amdgcn_mfma_f32_16x16x32_bf16(pf, vf, o_acc[nd], 0,0,0);
      }
    }
    __syncthreads();
  }

  #pragma unroll
  for (int nd = 0; nd < 4; nd++)
    #pragma unroll
    for (int r = 0; r < 4; r++){
      int t = qt*64 + wv*16 + ((lane>>4)<<2) + r;
      float val = o_acc[nd][r] / l_r[r];
      ao[((size_t)b*T + t)*DIM + hh*DH + nd*16 + (lane&15)] = f2bf(val);
    }
}

// ---------------- out projection + bias + residual (fp32 out) ----------------
__global__ __launch_bounds__(256) void out_gemm(const unsigned short* __restrict__ A,
      const unsigned short* __restrict__ Bt, const float* __restrict__ bout,
      const float* __restrict__ xres, float* __restrict__ out){
  int n0 = blockIdx.x*128, m0 = blockIdx.y*128;
  __shared__ unsigned short at[128*32];
  __shared__ unsigned short btile[128*32];
  int tid = threadIdx.x, lane = tid & 63, wv = tid >> 6;
  int wm = (wv >> 1)*64, wn = (wv & 1)*64;
  f32x4 acc[4][4];
  #pragma unroll
  for (int i = 0; i < 4; i++)
    #pragma unroll
    for (int j = 0; j < 4; j++) acc[i][j] = (f32x4){0.f,0.f,0.f,0.f};

  for (int k0 = 0; k0 < DIM; k0 += 32){
    #pragma unroll
    for (int c = 0; c < 2; c++){
      int idx = c*256 + tid;
      int row = idx >> 2, koff = (idx & 3)*16;
      gload_lds16((const char*)A  + ((size_t)(m0+row)*DIM + k0)*2 + koff,
                  (char*)at + (c*256 + wv*64)*16);
      gload_lds16((const char*)Bt + ((size_t)(n0+row)*DIM + k0)*2 + koff,
                  (char*)btile + (c*256 + wv*64)*16);
    }
    __syncthreads();
    bf16x8 af[4], bfv[4];
    #pragma unroll
    for (int i = 0; i < 4; i++){
      af[i]  = *reinterpret_cast<const bf16x8*>((const char*)at    + (wm + i*16 + (lane&15))*64 + (lane>>4)*16);
      bfv[i] = *reinterpret_cast<const bf16x8*>((const char*)btile + (wn + i*16 + (lane&15))*64 + (lane>>4)*16);
    }
    #pragma unroll
    for (int mi = 0; mi < 4; mi++)
      #pragma unroll
      for (int ni = 0; ni < 4; ni++)
        acc[mi][ni] = __builtin_amdgcn_mfma_f32_16x16x32_bf16(af[mi], bfv[ni], acc[mi][ni], 0,0,0);
    __syncthreads();
  }

  #pragma unroll
  for (int ni = 0; ni < 4; ni++){
    int gn = n0 + wn + ni*16 + (lane & 15);
    float bv = bout[gn];
    #pragma unroll
    for (int mi = 0; mi < 4; mi++){
      int gmb = m0 + wm + mi*16 + ((lane >> 4) << 2);
      #pragma unroll
      for (int r = 0; r < 4; r++){
        int gm = gmb + r;
        out[(size_t)gm*DIM + gn] = acc[mi][ni][r] + bv + xres[(size_t)gm*DIM + gn];
      }
    }
  }
}

extern "C" void kernel_launch(void* const* d_in, const int* in_sizes, int n_in,
                              void* d_out, int out_size, void* d_ws, size_t ws_size,
                              hipStream_t stream){
  const float* x    = (const float*)d_in[0];
  const float* ctx  = (const float*)d_in[1];
  const float* wqkv = (const float*)d_in[2];
  const float* bqkv = (const float*)d_in[3];
  const float* wout = (const float*)d_in[4];
  const float* bout = (const float*)d_in[5];
  const float* lng  = (const float*)d_in[6];
  const float* lnb  = (const float*)d_in[7];
  float* out = (float*)d_out;

  char* ws = (char*)d_ws;
  unsigned short* wqkvT  = (unsigned short*)ws; ws += (size_t)3072*1024*2;
  unsigned short* woutT  = (unsigned short*)ws; ws += (size_t)1024*1024*2;
  unsigned short* ln_all = (unsigned short*)ws; ws += (size_t)8192*1024*2;
  unsigned short* qbuf   = (unsigned short*)ws; ws += (size_t)BB*H*T*DH*2;
  unsigned short* kbuf   = (unsigned short*)ws; ws += (size_t)BB*H*L*DH*2;
  unsigned short* vtbuf  = (unsigned short*)ws; ws += (size_t)BB*H*DH*L*2;
  unsigned short* aobuf  = (unsigned short*)ws; ws += (size_t)BB*T*DIM*2;

  transpose_f32_bf16<<<dim3(3072/32, 1024/32), dim3(32,8), 0, stream>>>(wqkv, wqkvT, 1024, 3072);
  transpose_f32_bf16<<<dim3(1024/32, 1024/32), dim3(32,8), 0, stream>>>(wout, woutT, 1024, 1024);
  ln_kernel<<<dim3(8192), dim3(256), 0, stream>>>(x, ctx, lng, lnb, ln_all);
  qkv_gemm<<<dim3(3072/128, 8192/128), dim3(256), 0, stream>>>(ln_all, wqkvT, bqkv, qbuf, kbuf, vtbuf);
  attn_kernel<<<dim3(T/64, H, BB), dim3(256), 0, stream>>>(qbuf, kbuf, vtbuf, aobuf);
  out_gemm<<<dim3(1024/128, 4096/128), dim3(256), 0, stream>>>(aobuf, woutT, bout, x, out);
}

// Round 2
// 287.349 us; speedup vs baseline: 1.4326x; 1.4326x over previous
//
#include <hip/hip_runtime.h>
#include <stdint.h>

#define H 16
#define DH 64
#define T 2048
#define SS 2048
#define L 4096
#define DIM 1024
#define BB 2

typedef __bf16 bf16x8 __attribute__((ext_vector_type(8)));
typedef float f32x4 __attribute__((ext_vector_type(4)));

__device__ __forceinline__ unsigned short f2bf(float f){
  unsigned u = __builtin_bit_cast(unsigned, f);
  u += 0x7fff + ((u >> 16) & 1);
  return (unsigned short)(u >> 16);
}

__device__ __forceinline__ void gload_lds16(const void* g, void* l){
  void* gnc = const_cast<void*>(g);
  __builtin_amdgcn_global_load_lds((__attribute__((address_space(1))) void*)gnc,
                                   (__attribute__((address_space(3))) void*)l, 16, 0, 0);
}

// ---------------- LayerNorm (x rows then ctx rows) -> bf16 ----------------
__global__ __launch_bounds__(256) void ln_kernel(const float* __restrict__ x, const float* __restrict__ ctx,
                          const float* __restrict__ g, const float* __restrict__ b,
                          unsigned short* __restrict__ out){
  int row = blockIdx.x;
  int tid = threadIdx.x;
  const float* src = (row < BB*T) ? (x + (size_t)row*DIM) : (ctx + (size_t)(row - BB*T)*DIM);
  float4 v = reinterpret_cast<const float4*>(src)[tid];
  float s  = v.x + v.y + v.z + v.w;
  float s2 = v.x*v.x + v.y*v.y + v.z*v.z + v.w*v.w;
  #pragma unroll
  for (int off = 32; off > 0; off >>= 1){
    s  += __shfl_down(s,  off, 64);
    s2 += __shfl_down(s2, off, 64);
  }
  __shared__ float red[8];
  if ((tid & 63) == 0){ red[(tid>>6)*2] = s; red[(tid>>6)*2+1] = s2; }
  __syncthreads();
  s  = red[0] + red[2] + red[4] + red[6];
  s2 = red[1] + red[3] + red[5] + red[7];
  float mean = s * (1.0f/DIM);
  float var  = s2 * (1.0f/DIM) - mean*mean;
  float rstd = rsqrtf(var + 1e-5f);
  float4 gg = reinterpret_cast<const float4*>(g)[tid];
  float4 bv = reinterpret_cast<const float4*>(b)[tid];
  ushort4 o;
  o.x = f2bf((v.x-mean)*rstd*gg.x + bv.x);
  o.y = f2bf((v.y-mean)*rstd*gg.y + bv.y);
  o.z = f2bf((v.z-mean)*rstd*gg.z + bv.z);
  o.w = f2bf((v.w-mean)*rstd*gg.w + bv.w);
  reinterpret_cast<ushort4*>(out + (size_t)row*DIM)[tid] = o;
}

// ---------------- transpose fp32 [R][C] -> bf16 [C][R] ----------------
__global__ __launch_bounds__(256) void transpose_f32_bf16(const float* __restrict__ in,
                          unsigned short* __restrict__ out, int R, int C){
  __shared__ float tile[32][33];
  int c0 = blockIdx.x*32, r0 = blockIdx.y*32;
  int tx = threadIdx.x, ty = threadIdx.y;
  #pragma unroll
  for (int k = 0; k < 4; k++)
    tile[ty + k*8][tx] = in[(size_t)(r0 + ty + k*8)*C + c0 + tx];
  __syncthreads();
  #pragma unroll
  for (int k = 0; k < 4; k++)
    out[(size_t)(c0 + ty + k*8)*R + r0 + tx] = f2bf(tile[tx][ty + k*8]);
}

// ---------------- QKV GEMM: [8192 x 1024] @ [1024 x 3072], scatter epilogue ----------------
// Q is pre-scaled by (1/8)*log2(e) so attention softmax can run in exp2 domain.
__global__ __launch_bounds__(256) void qkv_gemm(const unsigned short* __restrict__ A,
      const unsigned short* __restrict__ Bt, const float* __restrict__ bias,
      unsigned short* __restrict__ qbuf, unsigned short* __restrict__ kbuf,
      unsigned short* __restrict__ vtbuf){
  int n0 = blockIdx.x*128, m0 = blockIdx.y*128;
  if (m0 >= BB*T && n0 < DIM) return;   // ctx rows need no Q columns
  __shared__ unsigned short at[128*32];
  __shared__ unsigned short btile[128*32];
  int tid = threadIdx.x, lane = tid & 63, wv = tid >> 6;
  int wm = (wv >> 1)*64, wn = (wv & 1)*64;
  f32x4 acc[4][4];
  #pragma unroll
  for (int i = 0; i < 4; i++)
    #pragma unroll
    for (int j = 0; j < 4; j++) acc[i][j] = (f32x4){0.f,0.f,0.f,0.f};

  for (int k0 = 0; k0 < DIM; k0 += 32){
    #pragma unroll
    for (int c = 0; c < 2; c++){
      int idx = c*256 + tid;
      int row = idx >> 2, koff = (idx & 3)*16;
      gload_lds16((const char*)A  + ((size_t)(m0+row)*DIM + k0)*2 + koff,
                  (char*)at + (c*256 + wv*64)*16);
      gload_lds16((const char*)Bt + ((size_t)(n0+row)*DIM + k0)*2 + koff,
                  (char*)btile + (c*256 + wv*64)*16);
    }
    __syncthreads();
    bf16x8 af[4], bfv[4];
    #pragma unroll
    for (int i = 0; i < 4; i++){
      af[i]  = *reinterpret_cast<const bf16x8*>((const char*)at    + (wm + i*16 + (lane&15))*64 + (lane>>4)*16);
      bfv[i] = *reinterpret_cast<const bf16x8*>((const char*)btile + (wn + i*16 + (lane&15))*64 + (lane>>4)*16);
    }
    #pragma unroll
    for (int mi = 0; mi < 4; mi++)
      #pragma unroll
      for (int ni = 0; ni < 4; ni++)
        acc[mi][ni] = __builtin_amdgcn_mfma_f32_16x16x32_bf16(af[mi], bfv[ni], acc[mi][ni], 0,0,0);
    __syncthreads();
  }

  #pragma unroll
  for (int ni = 0; ni < 4; ni++){
    int gn = n0 + wn + ni*16 + (lane & 15);
    float bv = bias[gn];
    int sec = gn >> 10, cc = gn & 1023, hh = cc >> 6, d = cc & 63;
    #pragma unroll
    for (int mi = 0; mi < 4; mi++){
      int gmb = m0 + wm + mi*16 + ((lane >> 4) << 2);
      bool isctx = gmb >= BB*T;
      int rm = isctx ? gmb - BB*T : gmb;
      int bidx = rm >> 11, tt = rm & 2047;
      size_t bh = (size_t)bidx*H + hh;
      if (sec == 0){
        if (isctx) continue;
        #pragma unroll
        for (int r = 0; r < 4; r++)
          qbuf[(bh*T + tt + r)*DH + d] = f2bf((acc[mi][ni][r] + bv)*0.18033688f); // 0.125*log2(e)
      } else if (sec == 1){
        int j = isctx ? T + tt : tt;
        #pragma unroll
        for (int r = 0; r < 4; r++)
          kbuf[(bh*L + j + r)*DH + d] = f2bf(acc[mi][ni][r] + bv);
      } else {
        int j = isctx ? T + tt : tt;
        ushort4 o;
        o.x = f2bf(acc[mi][ni][0] + bv);
        o.y = f2bf(acc[mi][ni][1] + bv);
        o.z = f2bf(acc[mi][ni][2] + bv);
        o.w = f2bf(acc[mi][ni][3] + bv);
        *reinterpret_cast<ushort4*>(vtbuf + (bh*DH + d)*L + j) = o;
      }
    }
  }
}

// ---------------- flash attention: swapped QK^T, swizzled LDS, 2-phase dbuf ----------------
// K LDS tile: [64 kv][64 d] bf16, chunk(16B)-swizzled: LDS[row][c] = G[row][c ^ (row&7)]
// V LDS tile: [64 d][64 kv] bf16, same swizzle.  P LDS: [16 q][64 kv] per wave, same swizzle.
__global__ __launch_bounds__(256) void attn_kernel(const unsigned short* __restrict__ q,
      const unsigned short* __restrict__ kbuf, const unsigned short* __restrict__ vtbuf,
      unsigned short* __restrict__ ao){
  int qt = blockIdx.x, hh = blockIdx.y, b = blockIdx.z;
  int tid = threadIdx.x, lane = tid & 63, wv = tid >> 6;
  int g = lane >> 4, qr = lane & 15;
  __shared__ unsigned short kt[2][64*64];
  __shared__ unsigned short vtt[2][64*64];
  __shared__ unsigned short pbuf[4][16*64];
  size_t bh = (size_t)b*H + hh;
  int qrow = qt*64 + wv*16 + qr;
  const unsigned short* qp = q + (bh*T + qrow)*DH;
  bf16x8 qf0 = *reinterpret_cast<const bf16x8*>(qp + g*8);
  bf16x8 qf1 = *reinterpret_cast<const bf16x8*>(qp + 32 + g*8);
  float m_l = -1e30f, l_l = 0.f;     // running max/denом for q-row qr (replicated over g)
  f32x4 o_acc[4];
  #pragma unroll
  for (int nd = 0; nd < 4; nd++) o_acc[nd] = (f32x4){0.f,0.f,0.f,0.f};
  const char* kg = (const char*)(kbuf + bh*(size_t)L*DH);
  const char* vg = (const char*)(vtbuf + bh*(size_t)DH*L);

  #define STAGE(bufi, jt) { \
    _Pragma("unroll") \
    for (int c = 0; c < 2; c++){ \
      int idx = c*256 + tid; \
      int row = idx >> 3, c16 = idx & 7; \
      int sc16 = c16 ^ (row & 7); \
      gload_lds16(kg + (size_t)(jt)*8192 + row*128 + sc16*16, \
                  (char*)kt[bufi] + (c*256 + wv*64)*16); \
      gload_lds16(vg + (size_t)row*(L*2) + (jt)*128 + sc16*16, \
                  (char*)vtt[bufi] + (c*256 + wv*64)*16); \
    } }

  STAGE(0, 0);
  __syncthreads();

  for (int jt = 0; jt < L/64; ++jt){
    int bufi = jt & 1;
    if (jt + 1 < L/64) STAGE(bufi^1, jt+1);   // prefetch overlaps compute
    const char* kb = (const char*)kt[bufi];
    const char* vb = (const char*)vtt[bufi];

    // S^T = K @ Q^T : lane holds scores for q-row qr, kv = ni*16 + g*4 + r
    f32x4 sc[4];
    #pragma unroll
    for (int ni = 0; ni < 4; ni++){
      int rk = ni*16 + qr, sw = rk & 7;
      bf16x8 kf0 = *reinterpret_cast<const bf16x8*>(kb + rk*128 + ((g    ^ sw)*16));
      bf16x8 kf1 = *reinterpret_cast<const bf16x8*>(kb + rk*128 + (((4+g)^ sw)*16));
      f32x4 z = (f32x4){0.f,0.f,0.f,0.f};
      z = __builtin_amdgcn_mfma_f32_16x16x32_bf16(kf0, qf0, z, 0,0,0);
      sc[ni] = __builtin_amdgcn_mfma_f32_16x16x32_bf16(kf1, qf1, z, 0,0,0);
    }

    // online softmax in exp2 domain, lane-local row
    float tm = -1e30f;
    #pragma unroll
    for (int ni = 0; ni < 4; ni++)
      #pragma unroll
      for (int r = 0; r < 4; r++) tm = fmaxf(tm, sc[ni][r]);
    tm = fmaxf(tm, __shfl_xor(tm, 16, 64));
    tm = fmaxf(tm, __shfl_xor(tm, 32, 64));
    float mn = fmaxf(m_l, tm);
    float alpha = exp2f(m_l - mn);
    m_l = mn;
    float ps = 0.f;
    #pragma unroll
    for (int ni = 0; ni < 4; ni++)
      #pragma unroll
      for (int r = 0; r < 4; r++){
        float p = exp2f(sc[ni][r] - mn);
        sc[ni][r] = p; ps += p;
      }
    ps += __shfl_xor(ps, 16, 64);
    ps += __shfl_xor(ps, 32, 64);
    l_l = l_l*alpha + ps;

    float ar[4];
    #pragma unroll
    for (int r = 0; r < 4; r++) ar[r] = __shfl(alpha, g*4 + r, 64);
    #pragma unroll
    for (int nd = 0; nd < 4; nd++)
      #pragma unroll
      for (int r = 0; r < 4; r++) o_acc[nd][r] *= ar[r];

    // P -> LDS (A-layout, swizzled): row qr, kv cols ni*16+g*4..+3  (8B store)
    #pragma unroll
    for (int ni = 0; ni < 4; ni++){
      ushort4 o;
      o.x = f2bf(sc[ni][0]); o.y = f2bf(sc[ni][1]);
      o.z = f2bf(sc[ni][2]); o.w = f2bf(sc[ni][3]);
      int c = ni*2 + (g>>1);
      *reinterpret_cast<ushort4*>((char*)pbuf[wv] + qr*128 + ((c ^ (qr&7))*16) + (g&1)*8) = o;
    }
    asm volatile("" ::: "memory");

    // O += P @ V^T
    #pragma unroll
    for (int kk = 0; kk < 2; kk++){
      bf16x8 pf = *reinterpret_cast<const bf16x8*>((char*)pbuf[wv] + qr*128 + (((kk*4+g) ^ (qr&7))*16));
      #pragma unroll
      for (int nd = 0; nd < 4; nd++){
        int rv = nd*16 + qr;
        bf16x8 vf = *reinterpret_cast<const bf16x8*>(vb + rv*128 + (((kk*4+g) ^ (rv&7))*16));
        o_acc[nd] = __builtin_amdgcn_mfma_f32_16x16x32_bf16(pf, vf, o_acc[nd], 0,0,0);
      }
    }
    __syncthreads();   // drains prefetch vmcnt + protects kt/vtt reuse
  }

  float lr[4];
  #pragma unroll
  for (int r = 0; r < 4; r++) lr[r] = 1.0f / __shfl(l_l, g*4 + r, 64);
  #pragma unroll
  for (int nd = 0; nd < 4; nd++)
    #pragma unroll
    for (int r = 0; r < 4; r++){
      int t = qt*64 + wv*16 + g*4 + r;
      ao[((size_t)b*T + t)*DIM + hh*DH + nd*16 + qr] = f2bf(o_acc[nd][r] * lr[r]);
    }
}

// ---------------- out projection + bias + residual (fp32 out) ----------------
__global__ __launch_bounds__(256) void out_gemm(const unsigned short* __restrict__ A,
      const unsigned short* __restrict__ Bt, const float* __restrict__ bout,
      const float* __restrict__ xres, float* __restrict__ out){
  int n0 = blockIdx.x*128, m0 = blockIdx.y*128;
  __shared__ unsigned short at[128*32];
  __shared__ unsigned short btile[128*32];
  int tid = threadIdx.x, lane = tid & 63, wv = tid >> 6;
  int wm = (wv >> 1)*64, wn = (wv & 1)*64;
  f32x4 acc[4][4];
  #pragma unroll
  for (int i = 0; i < 4; i++)
    #pragma unroll
    for (int j = 0; j < 4; j++) acc[i][j] = (f32x4){0.f,0.f,0.f,0.f};

  for (int k0 = 0; k0 < DIM; k0 += 32){
    #pragma unroll
    for (int c = 0; c < 2; c++){
      int idx = c*256 + tid;
      int row = idx >> 2, koff = (idx & 3)*16;
      gload_lds16((const char*)A  + ((size_t)(m0+row)*DIM + k0)*2 + koff,
                  (char*)at + (c*256 + wv*64)*16);
      gload_lds16((const char*)Bt + ((size_t)(n0+row)*DIM + k0)*2 + koff,
                  (char*)btile + (c*256 + wv*64)*16);
    }
    __syncthreads();
    bf16x8 af[4], bfv[4];
    #pragma unroll
    for (int i = 0; i < 4; i++){
      af[i]  = *reinterpret_cast<const bf16x8*>((const char*)at    + (wm + i*16 + (lane&15))*64 + (lane>>4)*16);
      bfv[i] = *reinterpret_cast<const bf16x8*>((const char*)btile + (wn + i*16 + (lane&15))*64 + (lane>>4)*16);
    }
    #pragma unroll
    for (int mi = 0; mi < 4; mi++)
      #pragma unroll
      for (int ni = 0; ni < 4; ni++)
        acc[mi][ni] = __builtin_amdgcn_mfma_f32_16x16x32_bf16(af[mi], bfv[ni], acc[mi][ni], 0,0,0);
    __syncthreads();
  }

  #pragma unroll
  for (int ni = 0; ni < 4; ni++){
    int gn = n0 + wn + ni*16 + (lane & 15);
    float bv = bout[gn];
    #pragma unroll
    for (int mi = 0; mi < 4; mi++){
      int gmb = m0 + wm + mi*16 + ((lane >> 4) << 2);
      #pragma unroll
      for (int r = 0; r < 4; r++){
        int gm = gmb + r;
        out[(size_t)gm*DIM + gn] = acc[mi][ni][r] + bv + xres[(size_t)gm*DIM + gn];
      }
    }
  }
}

extern "C" void kernel_launch(void* const* d_in, const int* in_sizes, int n_in,
                              void* d_out, int out_size, void* d_ws, size_t ws_size,
                              hipStream_t stream){
  const float* x    = (const float*)d_in[0];
  const float* ctx  = (const float*)d_in[1];
  const float* wqkv = (const float*)d_in[2];
  const float* bqkv = (const float*)d_in[3];
  const float* wout = (const float*)d_in[4];
  const float* bout = (const float*)d_in[5];
  const float* lng  = (const float*)d_in[6];
  const float* lnb  = (const float*)d_in[7];
  float* out = (float*)d_out;

  char* ws = (char*)d_ws;
  unsigned short* wqkvT  = (unsigned short*)ws; ws += (size_t)3072*1024*2;
  unsigned short* woutT  = (unsigned short*)ws; ws += (size_t)1024*1024*2;
  unsigned short* ln_all = (unsigned short*)ws; ws += (size_t)8192*1024*2;
  unsigned short* qbuf   = (unsigned short*)ws; ws += (size_t)BB*H*T*DH*2;
  unsigned short* kbuf   = (unsigned short*)ws; ws += (size_t)BB*H*L*DH*2;
  unsigned short* vtbuf  = (unsigned short*)ws; ws += (size_t)BB*H*DH*L*2;
  unsigned short* aobuf  = (unsigned short*)ws; ws += (size_t)BB*T*DIM*2;

  transpose_f32_bf16<<<dim3(3072/32, 1024/32), dim3(32,8), 0, stream>>>(wqkv, wqkvT, 1024, 3072);
  transpose_f32_bf16<<<dim3(1024/32, 1024/32), dim3(32,8), 0, stream>>>(wout, woutT, 1024, 1024);
  ln_kernel<<<dim3(8192), dim3(256), 0, stream>>>(x, ctx, lng, lnb, ln_all);
  qkv_gemm<<<dim3(3072/128, 8192/128), dim3(256), 0, stream>>>(ln_all, wqkvT, bqkv, qbuf, kbuf, vtbuf);
  attn_kernel<<<dim3(T/64, H, BB), dim3(256), 0, stream>>>(qbuf, kbuf, vtbuf, aobuf);
  out_gemm<<<dim3(1024/128, 4096/128), dim3(256), 0, stream>>>(aobuf, woutT, bout, x, out);
}

// Round 3
// 271.641 us; speedup vs baseline: 1.5155x; 1.0578x over previous
//
#include <hip/hip_runtime.h>
#include <stdint.h>

#define H 16
#define DH 64
#define T 2048
#define SS 2048
#define L 4096
#define DIM 1024
#define BB 2

typedef __bf16 bf16x8 __attribute__((ext_vector_type(8)));
typedef __bf16 bf16x4v __attribute__((ext_vector_type(4)));
typedef float f32x4 __attribute__((ext_vector_type(4)));

__device__ __forceinline__ unsigned short f2bf(float f){
  unsigned u = __builtin_bit_cast(unsigned, f);
  u += 0x7fff + ((u >> 16) & 1);
  return (unsigned short)(u >> 16);
}

__device__ __forceinline__ void gload_lds16(const void* g, void* l){
  void* gnc = const_cast<void*>(g);
  __builtin_amdgcn_global_load_lds((__attribute__((address_space(1))) void*)gnc,
                                   (__attribute__((address_space(3))) void*)l, 16, 0, 0);
}

// ---------------- LayerNorm (x rows then ctx rows) -> bf16 ----------------
__global__ __launch_bounds__(256) void ln_kernel(const float* __restrict__ x, const float* __restrict__ ctx,
                          const float* __restrict__ g, const float* __restrict__ b,
                          unsigned short* __restrict__ out){
  int row = blockIdx.x;
  int tid = threadIdx.x;
  const float* src = (row < BB*T) ? (x + (size_t)row*DIM) : (ctx + (size_t)(row - BB*T)*DIM);
  float4 v = reinterpret_cast<const float4*>(src)[tid];
  float s  = v.x + v.y + v.z + v.w;
  float s2 = v.x*v.x + v.y*v.y + v.z*v.z + v.w*v.w;
  #pragma unroll
  for (int off = 32; off > 0; off >>= 1){
    s  += __shfl_down(s,  off, 64);
    s2 += __shfl_down(s2, off, 64);
  }
  __shared__ float red[8];
  if ((tid & 63) == 0){ red[(tid>>6)*2] = s; red[(tid>>6)*2+1] = s2; }
  __syncthreads();
  s  = red[0] + red[2] + red[4] + red[6];
  s2 = red[1] + red[3] + red[5] + red[7];
  float mean = s * (1.0f/DIM);
  float var  = s2 * (1.0f/DIM) - mean*mean;
  float rstd = rsqrtf(var + 1e-5f);
  float4 gg = reinterpret_cast<const float4*>(g)[tid];
  float4 bv = reinterpret_cast<const float4*>(b)[tid];
  ushort4 o;
  o.x = f2bf((v.x-mean)*rstd*gg.x + bv.x);
  o.y = f2bf((v.y-mean)*rstd*gg.y + bv.y);
  o.z = f2bf((v.z-mean)*rstd*gg.z + bv.z);
  o.w = f2bf((v.w-mean)*rstd*gg.w + bv.w);
  reinterpret_cast<ushort4*>(out + (size_t)row*DIM)[tid] = o;
}

// ---------------- transpose fp32 [R][C] -> bf16 [C][R] ----------------
__global__ __launch_bounds__(256) void transpose_f32_bf16(const float* __restrict__ in,
                          unsigned short* __restrict__ out, int R, int C){
  __shared__ float tile[32][33];
  int c0 = blockIdx.x*32, r0 = blockIdx.y*32;
  int tx = threadIdx.x, ty = threadIdx.y;
  #pragma unroll
  for (int k = 0; k < 4; k++)
    tile[ty + k*8][tx] = in[(size_t)(r0 + ty + k*8)*C + c0 + tx];
  __syncthreads();
  #pragma unroll
  for (int k = 0; k < 4; k++)
    out[(size_t)(c0 + ty + k*8)*R + r0 + tx] = f2bf(tile[tx][ty + k*8]);
}

// ---------------- QKV GEMM: [8192 x 1024] @ [1024 x 3072], scatter epilogue ----------------
// Q is pre-scaled by (1/8)*log2(e) so attention softmax can run in exp2 domain.
__global__ __launch_bounds__(256) void qkv_gemm(const unsigned short* __restrict__ A,
      const unsigned short* __restrict__ Bt, const float* __restrict__ bias,
      unsigned short* __restrict__ qbuf, unsigned short* __restrict__ kbuf,
      unsigned short* __restrict__ vtbuf){
  int n0 = blockIdx.x*128, m0 = blockIdx.y*128;
  if (m0 >= BB*T && n0 < DIM) return;   // ctx rows need no Q columns
  __shared__ unsigned short at[128*32];
  __shared__ unsigned short btile[128*32];
  int tid = threadIdx.x, lane = tid & 63, wv = tid >> 6;
  int wm = (wv >> 1)*64, wn = (wv & 1)*64;
  f32x4 acc[4][4];
  #pragma unroll
  for (int i = 0; i < 4; i++)
    #pragma unroll
    for (int j = 0; j < 4; j++) acc[i][j] = (f32x4){0.f,0.f,0.f,0.f};

  for (int k0 = 0; k0 < DIM; k0 += 32){
    #pragma unroll
    for (int c = 0; c < 2; c++){
      int idx = c*256 + tid;
      int row = idx >> 2, koff = (idx & 3)*16;
      gload_lds16((const char*)A  + ((size_t)(m0+row)*DIM + k0)*2 + koff,
                  (char*)at + (c*256 + wv*64)*16);
      gload_lds16((const char*)Bt + ((size_t)(n0+row)*DIM + k0)*2 + koff,
                  (char*)btile + (c*256 + wv*64)*16);
    }
    __syncthreads();
    bf16x8 af[4], bfv[4];
    #pragma unroll
    for (int i = 0; i < 4; i++){
      af[i]  = *reinterpret_cast<const bf16x8*>((const char*)at    + (wm + i*16 + (lane&15))*64 + (lane>>4)*16);
      bfv[i] = *reinterpret_cast<const bf16x8*>((const char*)btile + (wn + i*16 + (lane&15))*64 + (lane>>4)*16);
    }
    #pragma unroll
    for (int mi = 0; mi < 4; mi++)
      #pragma unroll
      for (int ni = 0; ni < 4; ni++)
        acc[mi][ni] = __builtin_amdgcn_mfma_f32_16x16x32_bf16(af[mi], bfv[ni], acc[mi][ni], 0,0,0);
    __syncthreads();
  }

  #pragma unroll
  for (int ni = 0; ni < 4; ni++){
    int gn = n0 + wn + ni*16 + (lane & 15);
    float bv = bias[gn];
    int sec = gn >> 10, cc = gn & 1023, hh = cc >> 6, d = cc & 63;
    #pragma unroll
    for (int mi = 0; mi < 4; mi++){
      int gmb = m0 + wm + mi*16 + ((lane >> 4) << 2);
      bool isctx = gmb >= BB*T;
      int rm = isctx ? gmb - BB*T : gmb;
      int bidx = rm >> 11, tt = rm & 2047;
      size_t bh = (size_t)bidx*H + hh;
      if (sec == 0){
        if (isctx) continue;
        #pragma unroll
        for (int r = 0; r < 4; r++)
          qbuf[(bh*T + tt + r)*DH + d] = f2bf((acc[mi][ni][r] + bv)*0.18033688f); // 0.125*log2(e)
      } else if (sec == 1){
        int j = isctx ? T + tt : tt;
        #pragma unroll
        for (int r = 0; r < 4; r++)
          kbuf[(bh*L + j + r)*DH + d] = f2bf(acc[mi][ni][r] + bv);
      } else {
        int j = isctx ? T + tt : tt;
        ushort4 o;
        o.x = f2bf(acc[mi][ni][0] + bv);
        o.y = f2bf(acc[mi][ni][1] + bv);
        o.z = f2bf(acc[mi][ni][2] + bv);
        o.w = f2bf(acc[mi][ni][3] + bv);
        *reinterpret_cast<ushort4*>(vtbuf + (bh*DH + d)*L + j) = o;
      }
    }
  }
}

// ---------------- flash attention: 2 waves x 32 q-rows, swapped QK^T, swizzled LDS ----------------
// K LDS: [64 kv][64 d] bf16 swizzled LDS[row][c16] = G[row][c16 ^ (row&7)]
// V LDS: [64 d][64 kv] same swizzle.  P LDS: [32 q][64 kv] per wave, same swizzle.
// l accumulated via mfma(P, ones) on the idle matrix pipe; defer-max (THR=8, exp2 domain).
__global__ __launch_bounds__(128) void attn_kernel(const unsigned short* __restrict__ q,
      const unsigned short* __restrict__ kbuf, const unsigned short* __restrict__ vtbuf,
      unsigned short* __restrict__ ao){
  int qt = blockIdx.x, hh = blockIdx.y, b = blockIdx.z;
  int tid = threadIdx.x, lane = tid & 63, wv = tid >> 6;   // wv in {0,1}
  int g = lane >> 4, qr = lane & 15;
  __shared__ unsigned short kt[2][64*64];
  __shared__ unsigned short vtt[2][64*64];
  __shared__ unsigned short pbuf[2][32*64];
  size_t bh = (size_t)b*H + hh;
  int qbase = qt*64 + wv*32;

  bf16x8 qf[2][2];
  #pragma unroll
  for (int jq = 0; jq < 2; jq++){
    const unsigned short* qp = q + (bh*T + qbase + jq*16 + qr)*DH;
    qf[jq][0] = *reinterpret_cast<const bf16x8*>(qp + g*8);
    qf[jq][1] = *reinterpret_cast<const bf16x8*>(qp + 32 + g*8);
  }
  bf16x8 ones;
  #pragma unroll
  for (int j = 0; j < 8; j++) ones[j] = (__bf16)1.0f;

  float m_l[2] = {-1e30f, -1e30f};
  f32x4 acc_l[2];
  f32x4 o_acc[2][4];
  #pragma unroll
  for (int jq = 0; jq < 2; jq++){
    acc_l[jq] = (f32x4){0.f,0.f,0.f,0.f};
    #pragma unroll
    for (int nd = 0; nd < 4; nd++) o_acc[jq][nd] = (f32x4){0.f,0.f,0.f,0.f};
  }
  const char* kg = (const char*)(kbuf + bh*(size_t)L*DH);
  const char* vg = (const char*)(vtbuf + bh*(size_t)DH*L);

  #define STAGE(bufi, jt) { \
    _Pragma("unroll") \
    for (int c = 0; c < 4; c++){ \
      int idx = c*128 + tid; \
      int row = idx >> 3, c16 = idx & 7; \
      int sc16 = c16 ^ (row & 7); \
      gload_lds16(kg + (size_t)(jt)*8192 + row*128 + sc16*16, \
                  (char*)kt[bufi] + (c*128 + wv*64)*16); \
      gload_lds16(vg + (size_t)row*(L*2) + (jt)*128 + sc16*16, \
                  (char*)vtt[bufi] + (c*128 + wv*64)*16); \
    } }

  STAGE(0, 0);
  __syncthreads();

  for (int jt = 0; jt < L/64; ++jt){
    int bufi = jt & 1;
    if (jt + 1 < L/64) STAGE(bufi^1, jt+1);   // prefetch overlaps compute
    const char* kb = (const char*)kt[bufi];
    const char* vb = (const char*)vtt[bufi];

    // S^T = K @ Q^T : lane holds scores for q-row (jq*16+qr), kv = ni*16 + g*4 + r
    f32x4 sc[2][4];
    #pragma unroll
    for (int ni = 0; ni < 4; ni++){
      int rk = ni*16 + qr, sw = rk & 7;
      bf16x8 kf0 = *reinterpret_cast<const bf16x8*>(kb + rk*128 + ((g    ^ sw)*16));
      bf16x8 kf1 = *reinterpret_cast<const bf16x8*>(kb + rk*128 + (((4+g)^ sw)*16));
      #pragma unroll
      for (int jq = 0; jq < 2; jq++){
        f32x4 z = (f32x4){0.f,0.f,0.f,0.f};
        z = __builtin_amdgcn_mfma_f32_16x16x32_bf16(kf0, qf[jq][0], z, 0,0,0);
        sc[jq][ni] = __builtin_amdgcn_mfma_f32_16x16x32_bf16(kf1, qf[jq][1], z, 0,0,0);
      }
    }

    // online softmax (exp2 domain), defer-max with THR=8
    #pragma unroll
    for (int jq = 0; jq < 2; jq++){
      // max3-friendly tree over this lane's 16 scores
      float a0 = fmaxf(fmaxf(sc[jq][0][0], sc[jq][0][1]), sc[jq][0][2]);
      float a1 = fmaxf(fmaxf(sc[jq][0][3], sc[jq][1][0]), sc[jq][1][1]);
      float a2 = fmaxf(fmaxf(sc[jq][1][2], sc[jq][1][3]), sc[jq][2][0]);
      float a3 = fmaxf(fmaxf(sc[jq][2][1], sc[jq][2][2]), sc[jq][2][3]);
      float a4 = fmaxf(fmaxf(sc[jq][3][0], sc[jq][3][1]), sc[jq][3][2]);
      float tm = fmaxf(fmaxf(fmaxf(a0, a1), fmaxf(a2, a3)), fmaxf(a4, sc[jq][3][3]));
      if (!__all(tm - m_l[jq] <= 8.0f)){
        float tmf = fmaxf(tm, __shfl_xor(tm, 16, 64));
        tmf = fmaxf(tmf, __shfl_xor(tmf, 32, 64));
        float mn = fmaxf(m_l[jq], tmf);
        float alpha = exp2f(m_l[jq] - mn);
        m_l[jq] = mn;
        float ar[4];
        #pragma unroll
        for (int r = 0; r < 4; r++) ar[r] = __shfl(alpha, g*4 + r, 64);
        #pragma unroll
        for (int nd = 0; nd < 4; nd++)
          #pragma unroll
          for (int r = 0; r < 4; r++) o_acc[jq][nd][r] *= ar[r];
        #pragma unroll
        for (int r = 0; r < 4; r++) acc_l[jq][r] *= ar[r];
      }
      float mm = m_l[jq];
      int prow = jq*16 + qr;
      #pragma unroll
      for (int ni = 0; ni < 4; ni++){
        bf16x4v pv;
        pv[0] = (__bf16)exp2f(sc[jq][ni][0] - mm);
        pv[1] = (__bf16)exp2f(sc[jq][ni][1] - mm);
        pv[2] = (__bf16)exp2f(sc[jq][ni][2] - mm);
        pv[3] = (__bf16)exp2f(sc[jq][ni][3] - mm);
        int c = ni*2 + (g>>1);
        *reinterpret_cast<bf16x4v*>((char*)pbuf[wv] + prow*128 + ((c ^ (qr&7))*16) + (g&1)*8) = pv;
      }
    }
    asm volatile("" ::: "memory");

    // O += P @ V ; l += P @ ones  (wave-private pbuf, DS in-order per wave)
    #pragma unroll
    for (int jq = 0; jq < 2; jq++){
      int prow = jq*16 + qr;
      #pragma unroll
      for (int kk = 0; kk < 2; kk++){
        bf16x8 pf = *reinterpret_cast<const bf16x8*>((char*)pbuf[wv] + prow*128 + (((kk*4+g) ^ (qr&7))*16));
        #pragma unroll
        for (int nd = 0; nd < 4; nd++){
          int rv = nd*16 + qr;
          bf16x8 vf = *reinterpret_cast<const bf16x8*>(vb + rv*128 + (((kk*4+g) ^ (rv&7))*16));
          o_acc[jq][nd] = __builtin_amdgcn_mfma_f32_16x16x32_bf16(pf, vf, o_acc[jq][nd], 0,0,0);
        }
        acc_l[jq] = __builtin_amdgcn_mfma_f32_16x16x32_bf16(pf, ones, acc_l[jq], 0,0,0);
      }
    }
    __syncthreads();   // drains prefetch vmcnt + protects kt/vtt reuse
  }

  #pragma unroll
  for (int jq = 0; jq < 2; jq++)
    #pragma unroll
    for (int nd = 0; nd < 4; nd++)
      #pragma unroll
      for (int r = 0; r < 4; r++){
        int t = qbase + jq*16 + g*4 + r;
        float val = o_acc[jq][nd][r] / acc_l[jq][r];
        ao[((size_t)b*T + t)*DIM + hh*DH + nd*16 + qr] =
            __builtin_bit_cast(unsigned short, (__bf16)val);
      }
}

// ---------------- out projection + bias + residual (fp32 out) ----------------
__global__ __launch_bounds__(256) void out_gemm(const unsigned short* __restrict__ A,
      const unsigned short* __restrict__ Bt, const float* __restrict__ bout,
      const float* __restrict__ xres, float* __restrict__ out){
  int n0 = blockIdx.x*128, m0 = blockIdx.y*128;
  __shared__ unsigned short at[128*32];
  __shared__ unsigned short btile[128*32];
  int tid = threadIdx.x, lane = tid & 63, wv = tid >> 6;
  int wm = (wv >> 1)*64, wn = (wv & 1)*64;
  f32x4 acc[4][4];
  #pragma unroll
  for (int i = 0; i < 4; i++)
    #pragma unroll
    for (int j = 0; j < 4; j++) acc[i][j] = (f32x4){0.f,0.f,0.f,0.f};

  for (int k0 = 0; k0 < DIM; k0 += 32){
    #pragma unroll
    for (int c = 0; c < 2; c++){
      int idx = c*256 + tid;
      int row = idx >> 2, koff = (idx & 3)*16;
      gload_lds16((const char*)A  + ((size_t)(m0+row)*DIM + k0)*2 + koff,
                  (char*)at + (c*256 + wv*64)*16);
      gload_lds16((const char*)Bt + ((size_t)(n0+row)*DIM + k0)*2 + koff,
                  (char*)btile + (c*256 + wv*64)*16);
    }
    __syncthreads();
    bf16x8 af[4], bfv[4];
    #pragma unroll
    for (int i = 0; i < 4; i++){
      af[i]  = *reinterpret_cast<const bf16x8*>((const char*)at    + (wm + i*16 + (lane&15))*64 + (lane>>4)*16);
      bfv[i] = *reinterpret_cast<const bf16x8*>((const char*)btile + (wn + i*16 + (lane&15))*64 + (lane>>4)*16);
    }
    #pragma unroll
    for (int mi = 0; mi < 4; mi++)
      #pragma unroll
      for (int ni = 0; ni < 4; ni++)
        acc[mi][ni] = __builtin_amdgcn_mfma_f32_16x16x32_bf16(af[mi], bfv[ni], acc[mi][ni], 0,0,0);
    __syncthreads();
  }

  #pragma unroll
  for (int ni = 0; ni < 4; ni++){
    int gn = n0 + wn + ni*16 + (lane & 15);
    float bv = bout[gn];
    #pragma unroll
    for (int mi = 0; mi < 4; mi++){
      int gmb = m0 + wm + mi*16 + ((lane >> 4) << 2);
      #pragma unroll
      for (int r = 0; r < 4; r++){
        int gm = gmb + r;
        out[(size_t)gm*DIM + gn] = acc[mi][ni][r] + bv + xres[(size_t)gm*DIM + gn];
      }
    }
  }
}

extern "C" void kernel_launch(void* const* d_in, const int* in_sizes, int n_in,
                              void* d_out, int out_size, void* d_ws, size_t ws_size,
                              hipStream_t stream){
  const float* x    = (const float*)d_in[0];
  const float* ctx  = (const float*)d_in[1];
  const float* wqkv = (const float*)d_in[2];
  const float* bqkv = (const float*)d_in[3];
  const float* wout = (const float*)d_in[4];
  const float* bout = (const float*)d_in[5];
  const float* lng  = (const float*)d_in[6];
  const float* lnb  = (const float*)d_in[7];
  float* out = (float*)d_out;

  char* ws = (char*)d_ws;
  unsigned short* wqkvT  = (unsigned short*)ws; ws += (size_t)3072*1024*2;
  unsigned short* woutT  = (unsigned short*)ws; ws += (size_t)1024*1024*2;
  unsigned short* ln_all = (unsigned short*)ws; ws += (size_t)8192*1024*2;
  unsigned short* qbuf   = (unsigned short*)ws; ws += (size_t)BB*H*T*DH*2;
  unsigned short* kbuf   = (unsigned short*)ws; ws += (size_t)BB*H*L*DH*2;
  unsigned short* vtbuf  = (unsigned short*)ws; ws += (size_t)BB*H*DH*L*2;
  unsigned short* aobuf  = (unsigned short*)ws; ws += (size_t)BB*T*DIM*2;

  transpose_f32_bf16<<<dim3(3072/32, 1024/32), dim3(32,8), 0, stream>>>(wqkv, wqkvT, 1024, 3072);
  transpose_f32_bf16<<<dim3(1024/32, 1024/32), dim3(32,8), 0, stream>>>(wout, woutT, 1024, 1024);
  ln_kernel<<<dim3(8192), dim3(256), 0, stream>>>(x, ctx, lng, lnb, ln_all);
  qkv_gemm<<<dim3(3072/128, 8192/128), dim3(256), 0, stream>>>(ln_all, wqkvT, bqkv, qbuf, kbuf, vtbuf);
  attn_kernel<<<dim3(T/64, H, BB), dim3(128), 0, stream>>>(qbuf, kbuf, vtbuf, aobuf);
  out_gemm<<<dim3(1024/128, 4096/128), dim3(256), 0, stream>>>(aobuf, woutT, bout, x, out);
}

// Round 4
// 258.593 us; speedup vs baseline: 1.5919x; 1.0505x over previous
//
#include <hip/hip_runtime.h>
#include <stdint.h>

#define H 16
#define DH 64
#define T 2048
#define SS 2048
#define L 4096
#define DIM 1024
#define BB 2

typedef __bf16 bf16x8 __attribute__((ext_vector_type(8)));
typedef float f32x4 __attribute__((ext_vector_type(4)));
typedef float f32x16 __attribute__((ext_vector_type(16)));
typedef unsigned u32x4 __attribute__((ext_vector_type(4)));

__device__ __forceinline__ unsigned short f2bf(float f){
  unsigned u = __builtin_bit_cast(unsigned, f);
  u += 0x7fff + ((u >> 16) & 1);
  return (unsigned short)(u >> 16);
}

__device__ __forceinline__ unsigned cvt_pk_bf16(float lo, float hi){
  unsigned r;
  asm("v_cvt_pk_bf16_f32 %0, %1, %2" : "=v"(r) : "v"(lo), "v"(hi));
  return r;
}

__device__ __forceinline__ void gload_lds16(const void* g, void* l){
  void* gnc = const_cast<void*>(g);
  __builtin_amdgcn_global_load_lds((__attribute__((address_space(1))) void*)gnc,
                                   (__attribute__((address_space(3))) void*)l, 16, 0, 0);
}

// ---------------- LayerNorm (x rows then ctx rows) -> bf16 ----------------
__global__ __launch_bounds__(256) void ln_kernel(const float* __restrict__ x, const float* __restrict__ ctx,
                          const float* __restrict__ g, const float* __restrict__ b,
                          unsigned short* __restrict__ out){
  int row = blockIdx.x;
  int tid = threadIdx.x;
  const float* src = (row < BB*T) ? (x + (size_t)row*DIM) : (ctx + (size_t)(row - BB*T)*DIM);
  float4 v = reinterpret_cast<const float4*>(src)[tid];
  float s  = v.x + v.y + v.z + v.w;
  float s2 = v.x*v.x + v.y*v.y + v.z*v.z + v.w*v.w;
  #pragma unroll
  for (int off = 32; off > 0; off >>= 1){
    s  += __shfl_down(s,  off, 64);
    s2 += __shfl_down(s2, off, 64);
  }
  __shared__ float red[8];
  if ((tid & 63) == 0){ red[(tid>>6)*2] = s; red[(tid>>6)*2+1] = s2; }
  __syncthreads();
  s  = red[0] + red[2] + red[4] + red[6];
  s2 = red[1] + red[3] + red[5] + red[7];
  float mean = s * (1.0f/DIM);
  float var  = s2 * (1.0f/DIM) - mean*mean;
  float rstd = rsqrtf(var + 1e-5f);
  float4 gg = reinterpret_cast<const float4*>(g)[tid];
  float4 bv = reinterpret_cast<const float4*>(b)[tid];
  ushort4 o;
  o.x = f2bf((v.x-mean)*rstd*gg.x + bv.x);
  o.y = f2bf((v.y-mean)*rstd*gg.y + bv.y);
  o.z = f2bf((v.z-mean)*rstd*gg.z + bv.z);
  o.w = f2bf((v.w-mean)*rstd*gg.w + bv.w);
  reinterpret_cast<ushort4*>(out + (size_t)row*DIM)[tid] = o;
}

// ---------------- transpose fp32 [R][C] -> bf16 [C][R] ----------------
__global__ __launch_bounds__(256) void transpose_f32_bf16(const float* __restrict__ in,
                          unsigned short* __restrict__ out, int R, int C){
  __shared__ float tile[32][33];
  int c0 = blockIdx.x*32, r0 = blockIdx.y*32;
  int tx = threadIdx.x, ty = threadIdx.y;
  #pragma unroll
  for (int k = 0; k < 4; k++)
    tile[ty + k*8][tx] = in[(size_t)(r0 + ty + k*8)*C + c0 + tx];
  __syncthreads();
  #pragma unroll
  for (int k = 0; k < 4; k++)
    out[(size_t)(c0 + ty + k*8)*R + r0 + tx] = f2bf(tile[tx][ty + k*8]);
}

// ---------------- QKV GEMM: [8192 x 1024] @ [1024 x 3072], scatter epilogue ----------------
// Q is pre-scaled by (1/8)*log2(e) so attention softmax can run in exp2 domain.
__global__ __launch_bounds__(256) void qkv_gemm(const unsigned short* __restrict__ A,
      const unsigned short* __restrict__ Bt, const float* __restrict__ bias,
      unsigned short* __restrict__ qbuf, unsigned short* __restrict__ kbuf,
      unsigned short* __restrict__ vtbuf){
  int n0 = blockIdx.x*128, m0 = blockIdx.y*128;
  if (m0 >= BB*T && n0 < DIM) return;   // ctx rows need no Q columns
  __shared__ unsigned short at[128*32];
  __shared__ unsigned short btile[128*32];
  int tid = threadIdx.x, lane = tid & 63, wv = tid >> 6;
  int wm = (wv >> 1)*64, wn = (wv & 1)*64;
  f32x4 acc[4][4];
  #pragma unroll
  for (int i = 0; i < 4; i++)
    #pragma unroll
    for (int j = 0; j < 4; j++) acc[i][j] = (f32x4){0.f,0.f,0.f,0.f};

  for (int k0 = 0; k0 < DIM; k0 += 32){
    #pragma unroll
    for (int c = 0; c < 2; c++){
      int idx = c*256 + tid;
      int row = idx >> 2, koff = (idx & 3)*16;
      gload_lds16((const char*)A  + ((size_t)(m0+row)*DIM + k0)*2 + koff,
                  (char*)at + (c*256 + wv*64)*16);
      gload_lds16((const char*)Bt + ((size_t)(n0+row)*DIM + k0)*2 + koff,
                  (char*)btile + (c*256 + wv*64)*16);
    }
    __syncthreads();
    bf16x8 af[4], bfv[4];
    #pragma unroll
    for (int i = 0; i < 4; i++){
      af[i]  = *reinterpret_cast<const bf16x8*>((const char*)at    + (wm + i*16 + (lane&15))*64 + (lane>>4)*16);
      bfv[i] = *reinterpret_cast<const bf16x8*>((const char*)btile + (wn + i*16 + (lane&15))*64 + (lane>>4)*16);
    }
    #pragma unroll
    for (int mi = 0; mi < 4; mi++)
      #pragma unroll
      for (int ni = 0; ni < 4; ni++)
        acc[mi][ni] = __builtin_amdgcn_mfma_f32_16x16x32_bf16(af[mi], bfv[ni], acc[mi][ni], 0,0,0);
    __syncthreads();
  }

  #pragma unroll
  for (int ni = 0; ni < 4; ni++){
    int gn = n0 + wn + ni*16 + (lane & 15);
    float bv = bias[gn];
    int sec = gn >> 10, cc = gn & 1023, hh = cc >> 6, d = cc & 63;
    #pragma unroll
    for (int mi = 0; mi < 4; mi++){
      int gmb = m0 + wm + mi*16 + ((lane >> 4) << 2);
      bool isctx = gmb >= BB*T;
      int rm = isctx ? gmb - BB*T : gmb;
      int bidx = rm >> 11, tt = rm & 2047;
      size_t bh = (size_t)bidx*H + hh;
      if (sec == 0){
        if (isctx) continue;
        #pragma unroll
        for (int r = 0; r < 4; r++)
          qbuf[(bh*T + tt + r)*DH + d] = f2bf((acc[mi][ni][r] + bv)*0.18033688f); // 0.125*log2(e)
      } else if (sec == 1){
        int j = isctx ? T + tt : tt;
        #pragma unroll
        for (int r = 0; r < 4; r++)
          kbuf[(bh*L + j + r)*DH + d] = f2bf(acc[mi][ni][r] + bv);
      } else {
        int j = isctx ? T + tt : tt;
        ushort4 o;
        o.x = f2bf(acc[mi][ni][0] + bv);
        o.y = f2bf(acc[mi][ni][1] + bv);
        o.z = f2bf(acc[mi][ni][2] + bv);
        o.w = f2bf(acc[mi][ni][3] + bv);
        *reinterpret_cast<ushort4*>(vtbuf + (bh*DH + d)*L + j) = o;
      }
    }
  }
}

// ---------------- flash attention: 32x32 MFMA, in-register P via cvt_pk+permlane32_swap ----------
// 4 waves x 32 q-rows = 128 q/block. K LDS [64kv][64d], V LDS [64d][64kv], both chunk-swizzled
// LDS[row][c16] = G[row][c16 ^ (row&7)].  Swapped QK^T (mfma(K,Q)): lane owns q = lane&31,
// holds kv rows (reg&3)+8*(reg>>2)+4*(lane>>5) per 32-kv block.  P never touches LDS.
__global__ __launch_bounds__(256) void attn_kernel(const unsigned short* __restrict__ q,
      const unsigned short* __restrict__ kbuf, const unsigned short* __restrict__ vtbuf,
      unsigned short* __restrict__ ao){
  // XCD-aware swizzle: 512 blocks, 8 XCDs -> each XCD owns 4 complete (h,b) groups
  int hw = blockIdx.x;
  int wid = (hw & 7)*64 + (hw >> 3);
  int qt = wid & 15, hb = wid >> 4;
  int hh = hb & 15, b = hb >> 4;
  int tid = threadIdx.x, lane = tid & 63, wv = tid >> 6;  // 4 waves
  int hi = lane >> 5, q32 = lane & 31;
  __shared__ unsigned short kt[2][64*64];
  __shared__ unsigned short vtt[2][64*64];
  size_t bh = (size_t)b*H + hh;
  int qbase = qt*128 + wv*32;

  // Q fragments (B-operand): lane holds q-col = q32, k = d = ks*16 + hi*8 + j
  const unsigned short* qp = q + (bh*T + qbase + q32)*DH + hi*8;
  bf16x8 qf[4];
  #pragma unroll
  for (int ks = 0; ks < 4; ks++)
    qf[ks] = *reinterpret_cast<const bf16x8*>(qp + ks*16);

  f32x16 o_acc[2];
  #pragma unroll
  for (int d = 0; d < 2; d++)
    #pragma unroll
    for (int i = 0; i < 16; i++) o_acc[d][i] = 0.f;
  float m_l = -1e30f, l_acc = 0.f;

  const char* kg = (const char*)(kbuf + bh*(size_t)L*DH);
  const char* vg = (const char*)(vtbuf + bh*(size_t)DH*L);

  #define STAGE(bufi, jt) { \
    _Pragma("unroll") \
    for (int c = 0; c < 2; c++){ \
      int idx = c*256 + tid; \
      int row = idx >> 3, c16 = idx & 7; \
      int sc16 = c16 ^ (row & 7); \
      gload_lds16(kg + (size_t)(jt)*8192 + row*128 + sc16*16, \
                  (char*)kt[bufi] + (c*256 + wv*64)*16); \
      gload_lds16(vg + (size_t)row*(L*2) + (jt)*128 + sc16*16, \
                  (char*)vtt[bufi] + (c*256 + wv*64)*16); \
    } }

  STAGE(0, 0);
  __syncthreads();

  for (int jt = 0; jt < L/64; ++jt){
    int bufi = jt & 1;
    if (jt + 1 < L/64) STAGE(bufi^1, jt+1);   // prefetch overlaps compute
    const char* kb = (const char*)kt[bufi];
    const char* vb = (const char*)vtt[bufi];

    // S^T[kv][q]: two 32-kv blocks, chained over 4 k-steps of 16
    f32x16 sc[2];
    #pragma unroll
    for (int t = 0; t < 2; t++)
      #pragma unroll
      for (int i = 0; i < 16; i++) sc[t][i] = 0.f;
    #pragma unroll
    for (int ks = 0; ks < 4; ks++){
      #pragma unroll
      for (int t = 0; t < 2; t++){
        int row = t*32 + q32;
        bf16x8 kf = *reinterpret_cast<const bf16x8*>(kb + row*128 + (((ks*2+hi) ^ (row&7))*16));
        sc[t] = __builtin_amdgcn_mfma_f32_32x32x16_bf16(kf, qf[ks], sc[t], 0,0,0);
      }
    }

    // online softmax (exp2 domain), defer-max THR=8; lane-local q-row (halves on lane, lane+32)
    float tm = sc[0][0];
    #pragma unroll
    for (int t = 0; t < 2; t++)
      #pragma unroll
      for (int i = 0; i < 16; i++) tm = fmaxf(tm, sc[t][i]);
    if (!__all(tm - m_l <= 8.0f)){
      float tmf = fmaxf(tm, __shfl_xor(tm, 32, 64));
      float mn = fmaxf(m_l, tmf);
      float alpha = exp2f(m_l - mn);
      m_l = mn;
      #pragma unroll
      for (int d = 0; d < 2; d++)
        #pragma unroll
        for (int i = 0; i < 16; i++) o_acc[d][i] *= alpha;
      l_acc *= alpha;
    }
    #pragma unroll
    for (int t = 0; t < 2; t++)
      #pragma unroll
      for (int i = 0; i < 16; i++){
        float p = exp2f(sc[t][i] - m_l);
        sc[t][i] = p; l_acc += p;
      }

    // P^T -> B-fragments, in-register: 16 cvt_pk + 8 permlane32_swap
    bf16x8 pfrag[4];
    #pragma unroll
    for (int t = 0; t < 2; t++){
      #pragma unroll
      for (int half = 0; half < 2; half++){   // half=0: regs0-7 (ks=2t), half=1: regs8-15 (ks=2t+1)
        unsigned p01 = cvt_pk_bf16(sc[t][half*8+0], sc[t][half*8+1]);
        unsigned p23 = cvt_pk_bf16(sc[t][half*8+2], sc[t][half*8+3]);
        unsigned p45 = cvt_pk_bf16(sc[t][half*8+4], sc[t][half*8+5]);
        unsigned p67 = cvt_pk_bf16(sc[t][half*8+6], sc[t][half*8+7]);
        asm("v_permlane32_swap_b32 %0, %1" : "+v"(p01), "+v"(p45));
        asm("v_permlane32_swap_b32 %0, %1" : "+v"(p23), "+v"(p67));
        u32x4 w = (u32x4){p01, p23, p45, p67};
        pfrag[t*2 + half] = __builtin_bit_cast(bf16x8, w);
      }
    }

    // O^T[d][q] += V^T @ P^T
    #pragma unroll
    for (int ks = 0; ks < 4; ks++){
      #pragma unroll
      for (int d = 0; d < 2; d++){
        int row = d*32 + q32;
        bf16x8 vf = *reinterpret_cast<const bf16x8*>(vb + row*128 + (((ks*2+hi) ^ (row&7))*16));
        o_acc[d] = __builtin_amdgcn_mfma_f32_32x32x16_bf16(vf, pfrag[ks], o_acc[d], 0,0,0);
      }
    }
    __syncthreads();   // drains prefetch vmcnt + protects kt/vtt reuse
  }

  float l_tot = l_acc + __shfl_xor(l_acc, 32, 64);
  float inv = 1.0f / l_tot;
  unsigned short* aop = ao + ((size_t)b*T + qbase + q32)*DIM + hh*DH;
  #pragma unroll
  for (int d = 0; d < 2; d++)
    #pragma unroll
    for (int rg = 0; rg < 4; rg++){
      int d0 = d*32 + rg*8 + hi*4;
      ushort4 o;
      o.x = __builtin_bit_cast(unsigned short, (__bf16)(o_acc[d][rg*4+0]*inv));
      o.y = __builtin_bit_cast(unsigned short, (__bf16)(o_acc[d][rg*4+1]*inv));
      o.z = __builtin_bit_cast(unsigned short, (__bf16)(o_acc[d][rg*4+2]*inv));
      o.w = __builtin_bit_cast(unsigned short, (__bf16)(o_acc[d][rg*4+3]*inv));
      *reinterpret_cast<ushort4*>(aop + d0) = o;
    }
}

// ---------------- out projection + bias + residual (fp32 out) ----------------
__global__ __launch_bounds__(256) void out_gemm(const unsigned short* __restrict__ A,
      const unsigned short* __restrict__ Bt, const float* __restrict__ bout,
      const float* __restrict__ xres, float* __restrict__ out){
  int n0 = blockIdx.x*128, m0 = blockIdx.y*128;
  __shared__ unsigned short at[128*32];
  __shared__ unsigned short btile[128*32];
  int tid = threadIdx.x, lane = tid & 63, wv = tid >> 6;
  int wm = (wv >> 1)*64, wn = (wv & 1)*64;
  f32x4 acc[4][4];
  #pragma unroll
  for (int i = 0; i < 4; i++)
    #pragma unroll
    for (int j = 0; j < 4; j++) acc[i][j] = (f32x4){0.f,0.f,0.f,0.f};

  for (int k0 = 0; k0 < DIM; k0 += 32){
    #pragma unroll
    for (int c = 0; c < 2; c++){
      int idx = c*256 + tid;
      int row = idx >> 2, koff = (idx & 3)*16;
      gload_lds16((const char*)A  + ((size_t)(m0+row)*DIM + k0)*2 + koff,
                  (char*)at + (c*256 + wv*64)*16);
      gload_lds16((const char*)Bt + ((size_t)(n0+row)*DIM + k0)*2 + koff,
                  (char*)btile + (c*256 + wv*64)*16);
    }
    __syncthreads();
    bf16x8 af[4], bfv[4];
    #pragma unroll
    for (int i = 0; i < 4; i++){
      af[i]  = *reinterpret_cast<const bf16x8*>((const char*)at    + (wm + i*16 + (lane&15))*64 + (lane>>4)*16);
      bfv[i] = *reinterpret_cast<const bf16x8*>((const char*)btile + (wn + i*16 + (lane&15))*64 + (lane>>4)*16);
    }
    #pragma unroll
    for (int mi = 0; mi < 4; mi++)
      #pragma unroll
      for (int ni = 0; ni < 4; ni++)
        acc[mi][ni] = __builtin_amdgcn_mfma_f32_16x16x32_bf16(af[mi], bfv[ni], acc[mi][ni], 0,0,0);
    __syncthreads();
  }

  #pragma unroll
  for (int ni = 0; ni < 4; ni++){
    int gn = n0 + wn + ni*16 + (lane & 15);
    float bv = bout[gn];
    #pragma unroll
    for (int mi = 0; mi < 4; mi++){
      int gmb = m0 + wm + mi*16 + ((lane >> 4) << 2);
      #pragma unroll
      for (int r = 0; r < 4; r++){
        int gm = gmb + r;
        out[(size_t)gm*DIM + gn] = acc[mi][ni][r] + bv + xres[(size_t)gm*DIM + gn];
      }
    }
  }
}

extern "C" void kernel_launch(void* const* d_in, const int* in_sizes, int n_in,
                              void* d_out, int out_size, void* d_ws, size_t ws_size,
                              hipStream_t stream){
  const float* x    = (const float*)d_in[0];
  const float* ctx  = (const float*)d_in[1];
  const float* wqkv = (const float*)d_in[2];
  const float* bqkv = (const float*)d_in[3];
  const float* wout = (const float*)d_in[4];
  const float* bout = (const float*)d_in[5];
  const float* lng  = (const float*)d_in[6];
  const float* lnb  = (const float*)d_in[7];
  float* out = (float*)d_out;

  char* ws = (char*)d_ws;
  unsigned short* wqkvT  = (unsigned short*)ws; ws += (size_t)3072*1024*2;
  unsigned short* woutT  = (unsigned short*)ws; ws += (size_t)1024*1024*2;
  unsigned short* ln_all = (unsigned short*)ws; ws += (size_t)8192*1024*2;
  unsigned short* qbuf   = (unsigned short*)ws; ws += (size_t)BB*H*T*DH*2;
  unsigned short* kbuf   = (unsigned short*)ws; ws += (size_t)BB*H*L*DH*2;
  unsigned short* vtbuf  = (unsigned short*)ws; ws += (size_t)BB*H*DH*L*2;
  unsigned short* aobuf  = (unsigned short*)ws; ws += (size_t)BB*T*DIM*2;

  transpose_f32_bf16<<<dim3(3072/32, 1024/32), dim3(32,8), 0, stream>>>(wqkv, wqkvT, 1024, 3072);
  transpose_f32_bf16<<<dim3(1024/32, 1024/32), dim3(32,8), 0, stream>>>(wout, woutT, 1024, 1024);
  ln_kernel<<<dim3(8192), dim3(256), 0, stream>>>(x, ctx, lng, lnb, ln_all);
  qkv_gemm<<<dim3(3072/128, 8192/128), dim3(256), 0, stream>>>(ln_all, wqkvT, bqkv, qbuf, kbuf, vtbuf);
  attn_kernel<<<dim3(512), dim3(256), 0, stream>>>(qbuf, kbuf, vtbuf, aobuf);
  out_gemm<<<dim3(1024/128, 4096/128), dim3(256), 0, stream>>>(aobuf, woutT, bout, x, out);
}

// Round 5
// 250.628 us; speedup vs baseline: 1.6425x; 1.0318x over previous
//
#include <hip/hip_runtime.h>
#include <stdint.h>

#define H 16
#define DH 64
#define T 2048
#define SS 2048
#define L 4096
#define DIM 1024
#define BB 2

typedef __bf16 bf16x8 __attribute__((ext_vector_type(8)));
typedef float f32x4 __attribute__((ext_vector_type(4)));
typedef float f32x16 __attribute__((ext_vector_type(16)));
typedef unsigned u32x4 __attribute__((ext_vector_type(4)));

__device__ __forceinline__ unsigned short f2bf(float f){
  unsigned u = __builtin_bit_cast(unsigned, f);
  u += 0x7fff + ((u >> 16) & 1);
  return (unsigned short)(u >> 16);
}

__device__ __forceinline__ unsigned cvt_pk_bf16(float lo, float hi){
  unsigned r;
  asm("v_cvt_pk_bf16_f32 %0, %1, %2" : "=v"(r) : "v"(lo), "v"(hi));
  return r;
}

__device__ __forceinline__ float fmax3(float a, float b, float c){
  float r;
  asm("v_max3_f32 %0, %1, %2, %3" : "=v"(r) : "v"(a), "v"(b), "v"(c));
  return r;
}

__device__ __forceinline__ void gload_lds16(const void* g, void* l){
  void* gnc = const_cast<void*>(g);
  __builtin_amdgcn_global_load_lds((__attribute__((address_space(1))) void*)gnc,
                                   (__attribute__((address_space(3))) void*)l, 16, 0, 0);
}

// ---------------- LayerNorm (x rows then ctx rows) -> bf16 ----------------
__global__ __launch_bounds__(256) void ln_kernel(const float* __restrict__ x, const float* __restrict__ ctx,
                          const float* __restrict__ g, const float* __restrict__ b,
                          unsigned short* __restrict__ out){
  int row = blockIdx.x;
  int tid = threadIdx.x;
  const float* src = (row < BB*T) ? (x + (size_t)row*DIM) : (ctx + (size_t)(row - BB*T)*DIM);
  float4 v = reinterpret_cast<const float4*>(src)[tid];
  float s  = v.x + v.y + v.z + v.w;
  float s2 = v.x*v.x + v.y*v.y + v.z*v.z + v.w*v.w;
  #pragma unroll
  for (int off = 32; off > 0; off >>= 1){
    s  += __shfl_down(s,  off, 64);
    s2 += __shfl_down(s2, off, 64);
  }
  __shared__ float red[8];
  if ((tid & 63) == 0){ red[(tid>>6)*2] = s; red[(tid>>6)*2+1] = s2; }
  __syncthreads();
  s  = red[0] + red[2] + red[4] + red[6];
  s2 = red[1] + red[3] + red[5] + red[7];
  float mean = s * (1.0f/DIM);
  float var  = s2 * (1.0f/DIM) - mean*mean;
  float rstd = rsqrtf(var + 1e-5f);
  float4 gg = reinterpret_cast<const float4*>(g)[tid];
  float4 bv = reinterpret_cast<const float4*>(b)[tid];
  ushort4 o;
  o.x = f2bf((v.x-mean)*rstd*gg.x + bv.x);
  o.y = f2bf((v.y-mean)*rstd*gg.y + bv.y);
  o.z = f2bf((v.z-mean)*rstd*gg.z + bv.z);
  o.w = f2bf((v.w-mean)*rstd*gg.w + bv.w);
  reinterpret_cast<ushort4*>(out + (size_t)row*DIM)[tid] = o;
}

// ---------------- transpose fp32 [R][C] -> bf16 [C][R] ----------------
__global__ __launch_bounds__(256) void transpose_f32_bf16(const float* __restrict__ in,
                          unsigned short* __restrict__ out, int R, int C){
  __shared__ float tile[32][33];
  int c0 = blockIdx.x*32, r0 = blockIdx.y*32;
  int tx = threadIdx.x, ty = threadIdx.y;
  #pragma unroll
  for (int k = 0; k < 4; k++)
    tile[ty + k*8][tx] = in[(size_t)(r0 + ty + k*8)*C + c0 + tx];
  __syncthreads();
  #pragma unroll
  for (int k = 0; k < 4; k++)
    out[(size_t)(c0 + ty + k*8)*R + r0 + tx] = f2bf(tile[tx][ty + k*8]);
}

// ---------------- QKV GEMM: [8192 x 1024] @ [1024 x 3072], scatter epilogue ----------------
// Q is pre-scaled by (1/8)*log2(e) so attention softmax can run in exp2 domain.
__global__ __launch_bounds__(256) void qkv_gemm(const unsigned short* __restrict__ A,
      const unsigned short* __restrict__ Bt, const float* __restrict__ bias,
      unsigned short* __restrict__ qbuf, unsigned short* __restrict__ kbuf,
      unsigned short* __restrict__ vtbuf){
  // bijective XCD swizzle: 1536 blocks, 1536 % 8 == 0
  int orig = blockIdx.x;
  int wid = (orig & 7)*192 + (orig >> 3);
  int n0 = (wid % 24)*128, m0 = (wid / 24)*128;
  if (m0 >= BB*T && n0 < DIM) return;   // ctx rows need no Q columns
  __shared__ unsigned short at[128*32];
  __shared__ unsigned short btile[128*32];
  int tid = threadIdx.x, lane = tid & 63, wv = tid >> 6;
  int wm = (wv >> 1)*64, wn = (wv & 1)*64;
  f32x4 acc[4][4];
  #pragma unroll
  for (int i = 0; i < 4; i++)
    #pragma unroll
    for (int j = 0; j < 4; j++) acc[i][j] = (f32x4){0.f,0.f,0.f,0.f};

  for (int k0 = 0; k0 < DIM; k0 += 32){
    #pragma unroll
    for (int c = 0; c < 2; c++){
      int idx = c*256 + tid;
      int row = idx >> 2, koff = (idx & 3)*16;
      gload_lds16((const char*)A  + ((size_t)(m0+row)*DIM + k0)*2 + koff,
                  (char*)at + (c*256 + wv*64)*16);
      gload_lds16((const char*)Bt + ((size_t)(n0+row)*DIM + k0)*2 + koff,
                  (char*)btile + (c*256 + wv*64)*16);
    }
    __syncthreads();
    bf16x8 af[4], bfv[4];
    #pragma unroll
    for (int i = 0; i < 4; i++){
      af[i]  = *reinterpret_cast<const bf16x8*>((const char*)at    + (wm + i*16 + (lane&15))*64 + (lane>>4)*16);
      bfv[i] = *reinterpret_cast<const bf16x8*>((const char*)btile + (wn + i*16 + (lane&15))*64 + (lane>>4)*16);
    }
    #pragma unroll
    for (int mi = 0; mi < 4; mi++)
      #pragma unroll
      for (int ni = 0; ni < 4; ni++)
        acc[mi][ni] = __builtin_amdgcn_mfma_f32_16x16x32_bf16(af[mi], bfv[ni], acc[mi][ni], 0,0,0);
    __syncthreads();
  }

  #pragma unroll
  for (int ni = 0; ni < 4; ni++){
    int gn = n0 + wn + ni*16 + (lane & 15);
    float bv = bias[gn];
    int sec = gn >> 10, cc = gn & 1023, hh = cc >> 6, d = cc & 63;
    #pragma unroll
    for (int mi = 0; mi < 4; mi++){
      int gmb = m0 + wm + mi*16 + ((lane >> 4) << 2);
      bool isctx = gmb >= BB*T;
      int rm = isctx ? gmb - BB*T : gmb;
      int bidx = rm >> 11, tt = rm & 2047;
      size_t bh = (size_t)bidx*H + hh;
      if (sec == 0){
        if (isctx) continue;
        #pragma unroll
        for (int r = 0; r < 4; r++)
          qbuf[(bh*T + tt + r)*DH + d] = f2bf((acc[mi][ni][r] + bv)*0.18033688f); // 0.125*log2(e)
      } else if (sec == 1){
        int j = isctx ? T + tt : tt;
        #pragma unroll
        for (int r = 0; r < 4; r++)
          kbuf[(bh*L + j + r)*DH + d] = f2bf(acc[mi][ni][r] + bv);
      } else {
        int j = isctx ? T + tt : tt;
        ushort4 o;
        o.x = f2bf(acc[mi][ni][0] + bv);
        o.y = f2bf(acc[mi][ni][1] + bv);
        o.z = f2bf(acc[mi][ni][2] + bv);
        o.w = f2bf(acc[mi][ni][3] + bv);
        *reinterpret_cast<ushort4*>(vtbuf + (bh*DH + d)*L + j) = o;
      }
    }
  }
}

// ---------------- flash attention: 32x32 MFMA, KVBLK=128, in-register P -------------------
// 4 waves x 32 q = 128 q/block.  K LDS [128 kv][64 d] (8 chunks/row), V LDS [64 d][128 kv]
// (16 chunks/row), both chunk-swizzled: LDS[row][c16] = G[row][c16 ^ (row&7)].
// Swapped QK^T (mfma(K,Q)): lane owns q = lane&31.  P stays in registers (cvt_pk+permlane).
// l accumulated via mfma(ones, P) on the matrix pipe: every acc reg holds l, read reg 0.
__global__ __launch_bounds__(256) void attn_kernel(const unsigned short* __restrict__ q,
      const unsigned short* __restrict__ kbuf, const unsigned short* __restrict__ vtbuf,
      unsigned short* __restrict__ ao){
  // XCD-aware swizzle: 512 blocks, 8 XCDs -> each XCD owns 4 complete (h,b) groups
  int hw = blockIdx.x;
  int wid = (hw & 7)*64 + (hw >> 3);
  int qt = wid & 15, hb = wid >> 4;
  int hh = hb & 15, b = hb >> 4;
  int tid = threadIdx.x, lane = tid & 63, wv = tid >> 6;  // 4 waves
  int hi = lane >> 5, q32 = lane & 31;
  __shared__ unsigned short kt[2][128*64];
  __shared__ unsigned short vtt[2][64*128];
  size_t bh = (size_t)b*H + hh;
  int qbase = qt*128 + wv*32;

  // Q fragments (B-operand): lane holds q-col = q32, k = d = ks*16 + hi*8 + j
  const unsigned short* qp = q + (bh*T + qbase + q32)*DH + hi*8;
  bf16x8 qf[4];
  #pragma unroll
  for (int ks = 0; ks < 4; ks++)
    qf[ks] = *reinterpret_cast<const bf16x8*>(qp + ks*16);

  bf16x8 ones;
  #pragma unroll
  for (int j = 0; j < 8; j++) ones[j] = (__bf16)1.0f;

  f32x16 o_acc[2], l_vec;
  #pragma unroll
  for (int d = 0; d < 2; d++)
    #pragma unroll
    for (int i = 0; i < 16; i++) o_acc[d][i] = 0.f;
  #pragma unroll
  for (int i = 0; i < 16; i++) l_vec[i] = 0.f;
  float m_l = -1e30f;

  const char* kg = (const char*)(kbuf + bh*(size_t)L*DH);
  const char* vg = (const char*)(vtbuf + bh*(size_t)DH*L);

  // stage one 128-kv tile (32 KB): K rows 128x64, V rows 64x128
  #define STAGE(bufi, jt) { \
    _Pragma("unroll") \
    for (int c = 0; c < 4; c++){ \
      int idx = c*256 + tid; \
      int krow = idx >> 3, kc = idx & 7; \
      gload_lds16(kg + (size_t)((jt)*128 + krow)*128 + ((kc ^ (krow & 7))*16), \
                  (char*)kt[bufi] + (c*256 + wv*64)*16); \
      int vrow = idx >> 4, vc = idx & 15; \
      gload_lds16(vg + (size_t)vrow*(L*2) + (jt)*256 + ((vc ^ (vrow & 7))*16), \
                  (char*)vtt[bufi] + (c*256 + wv*64)*16); \
    } }

  STAGE(0, 0);
  __syncthreads();

  for (int jt = 0; jt < L/128; ++jt){
    int bufi = jt & 1;
    if (jt + 1 < L/128) STAGE(bufi^1, jt+1);   // prefetch overlaps compute
    const char* kb = (const char*)kt[bufi];
    const char* vb = (const char*)vtt[bufi];

    // S^T[kv][q]: four 32-kv blocks, chained over 4 k-steps of 16
    f32x16 sc[4];
    #pragma unroll
    for (int t = 0; t < 4; t++)
      #pragma unroll
      for (int i = 0; i < 16; i++) sc[t][i] = 0.f;
    #pragma unroll
    for (int ks = 0; ks < 4; ks++){
      #pragma unroll
      for (int t = 0; t < 4; t++){
        int row = t*32 + q32;
        bf16x8 kf = *reinterpret_cast<const bf16x8*>(kb + row*128 + (((ks*2+hi) ^ (row&7))*16));
        sc[t] = __builtin_amdgcn_mfma_f32_32x32x16_bf16(kf, qf[ks], sc[t], 0,0,0);
      }
    }

    // tile max via v_max3 tree (lane-local q-row; halves on lane, lane+32)
    float rt[4];
    #pragma unroll
    for (int t = 0; t < 4; t++){
      float v0 = fmax3(sc[t][0],  sc[t][1],  sc[t][2]);
      float v1 = fmax3(sc[t][3],  sc[t][4],  sc[t][5]);
      float v2 = fmax3(sc[t][6],  sc[t][7],  sc[t][8]);
      float v3 = fmax3(sc[t][9],  sc[t][10], sc[t][11]);
      float v4 = fmax3(sc[t][12], sc[t][13], sc[t][14]);
      rt[t] = fmaxf(fmax3(v0, v1, v2), fmax3(v3, v4, sc[t][15]));
    }
    float tm = fmaxf(fmax3(rt[0], rt[1], rt[2]), rt[3]);

    // online softmax (exp2 domain), defer-max THR=8
    if (!__all(tm - m_l <= 8.0f)){
      float tmf = fmaxf(tm, __shfl_xor(tm, 32, 64));
      float mn = fmaxf(m_l, tmf);
      float alpha = exp2f(m_l - mn);
      m_l = mn;
      #pragma unroll
      for (int d = 0; d < 2; d++)
        #pragma unroll
        for (int i = 0; i < 16; i++) o_acc[d][i] *= alpha;
      l_vec[0] *= alpha;   // only reg 0 is ever read; MFMA adds equally to all regs
    }
    #pragma unroll
    for (int t = 0; t < 4; t++)
      #pragma unroll
      for (int i = 0; i < 16; i++)
        sc[t][i] = exp2f(sc[t][i] - m_l);

    // P^T -> B-fragments, in-register: 32 cvt_pk + 16 permlane32_swap
    bf16x8 pfrag[8];
    #pragma unroll
    for (int t = 0; t < 4; t++){
      #pragma unroll
      for (int half = 0; half < 2; half++){
        unsigned p01 = cvt_pk_bf16(sc[t][half*8+0], sc[t][half*8+1]);
        unsigned p23 = cvt_pk_bf16(sc[t][half*8+2], sc[t][half*8+3]);
        unsigned p45 = cvt_pk_bf16(sc[t][half*8+4], sc[t][half*8+5]);
        unsigned p67 = cvt_pk_bf16(sc[t][half*8+6], sc[t][half*8+7]);
        asm("v_permlane32_swap_b32 %0, %1" : "+v"(p01), "+v"(p45));
        asm("v_permlane32_swap_b32 %0, %1" : "+v"(p23), "+v"(p67));
        u32x4 w = (u32x4){p01, p23, p45, p67};
        pfrag[t*2 + half] = __builtin_bit_cast(bf16x8, w);
      }
    }

    // O^T[d][q] += V^T @ P^T ; l_vec += ones @ P^T (row sums, all regs equal)
    #pragma unroll
    for (int ks = 0; ks < 8; ks++){
      #pragma unroll
      for (int d = 0; d < 2; d++){
        int row = d*32 + q32;
        bf16x8 vf = *reinterpret_cast<const bf16x8*>(vb + row*256 + (((ks*2+hi) ^ (row&7))*16));
        o_acc[d] = __builtin_amdgcn_mfma_f32_32x32x16_bf16(vf, pfrag[ks], o_acc[d], 0,0,0);
      }
      l_vec = __builtin_amdgcn_mfma_f32_32x32x16_bf16(ones, pfrag[ks], l_vec, 0,0,0);
    }
    __syncthreads();   // drains prefetch vmcnt + protects kt/vtt reuse
  }

  float inv = 1.0f / l_vec[0];
  unsigned short* aop = ao + ((size_t)b*T + qbase + q32)*DIM + hh*DH;
  #pragma unroll
  for (int d = 0; d < 2; d++)
    #pragma unroll
    for (int rg = 0; rg < 4; rg++){
      int d0 = d*32 + rg*8 + hi*4;
      ushort4 o;
      o.x = __builtin_bit_cast(unsigned short, (__bf16)(o_acc[d][rg*4+0]*inv));
      o.y = __builtin_bit_cast(unsigned short, (__bf16)(o_acc[d][rg*4+1]*inv));
      o.z = __builtin_bit_cast(unsigned short, (__bf16)(o_acc[d][rg*4+2]*inv));
      o.w = __builtin_bit_cast(unsigned short, (__bf16)(o_acc[d][rg*4+3]*inv));
      *reinterpret_cast<ushort4*>(aop + d0) = o;
    }
}

// ---------------- out projection + bias + residual (fp32 out) ----------------
__global__ __launch_bounds__(256) void out_gemm(const unsigned short* __restrict__ A,
      const unsigned short* __restrict__ Bt, const float* __restrict__ bout,
      const float* __restrict__ xres, float* __restrict__ out){
  int n0 = blockIdx.x*128, m0 = blockIdx.y*128;
  __shared__ unsigned short at[128*32];
  __shared__ unsigned short btile[128*32];
  int tid = threadIdx.x, lane = tid & 63, wv = tid >> 6;
  int wm = (wv >> 1)*64, wn = (wv & 1)*64;
  f32x4 acc[4][4];
  #pragma unroll
  for (int i = 0; i < 4; i++)
    #pragma unroll
    for (int j = 0; j < 4; j++) acc[i][j] = (f32x4){0.f,0.f,0.f,0.f};

  for (int k0 = 0; k0 < DIM; k0 += 32){
    #pragma unroll
    for (int c = 0; c < 2; c++){
      int idx = c*256 + tid;
      int row = idx >> 2, koff = (idx & 3)*16;
      gload_lds16((const char*)A  + ((size_t)(m0+row)*DIM + k0)*2 + koff,
                  (char*)at + (c*256 + wv*64)*16);
      gload_lds16((const char*)Bt + ((size_t)(n0+row)*DIM + k0)*2 + koff,
                  (char*)btile + (c*256 + wv*64)*16);
    }
    __syncthreads();
    bf16x8 af[4], bfv[4];
    #pragma unroll
    for (int i = 0; i < 4; i++){
      af[i]  = *reinterpret_cast<const bf16x8*>((const char*)at    + (wm + i*16 + (lane&15))*64 + (lane>>4)*16);
      bfv[i] = *reinterpret_cast<const bf16x8*>((const char*)btile + (wn + i*16 + (lane&15))*64 + (lane>>4)*16);
    }
    #pragma unroll
    for (int mi = 0; mi < 4; mi++)
      #pragma unroll
      for (int ni = 0; ni < 4; ni++)
        acc[mi][ni] = __builtin_amdgcn_mfma_f32_16x16x32_bf16(af[mi], bfv[ni], acc[mi][ni], 0,0,0);
    __syncthreads();
  }

  #pragma unroll
  for (int ni = 0; ni < 4; ni++){
    int gn = n0 + wn + ni*16 + (lane & 15);
    float bv = bout[gn];
    #pragma unroll
    for (int mi = 0; mi < 4; mi++){
      int gmb = m0 + wm + mi*16 + ((lane >> 4) << 2);
      #pragma unroll
      for (int r = 0; r < 4; r++){
        int gm = gmb + r;
        out[(size_t)gm*DIM + gn] = acc[mi][ni][r] + bv + xres[(size_t)gm*DIM + gn];
      }
    }
  }
}

extern "C" void kernel_launch(void* const* d_in, const int* in_sizes, int n_in,
                              void* d_out, int out_size, void* d_ws, size_t ws_size,
                              hipStream_t stream){
  const float* x    = (const float*)d_in[0];
  const float* ctx  = (const float*)d_in[1];
  const float* wqkv = (const float*)d_in[2];
  const float* bqkv = (const float*)d_in[3];
  const float* wout = (const float*)d_in[4];
  const float* bout = (const float*)d_in[5];
  const float* lng  = (const float*)d_in[6];
  const float* lnb  = (const float*)d_in[7];
  float* out = (float*)d_out;

  char* ws = (char*)d_ws;
  unsigned short* wqkvT  = (unsigned short*)ws; ws += (size_t)3072*1024*2;
  unsigned short* woutT  = (unsigned short*)ws; ws += (size_t)1024*1024*2;
  unsigned short* ln_all = (unsigned short*)ws; ws += (size_t)8192*1024*2;
  unsigned short* qbuf   = (unsigned short*)ws; ws += (size_t)BB*H*T*DH*2;
  unsigned short* kbuf   = (unsigned short*)ws; ws += (size_t)BB*H*L*DH*2;
  unsigned short* vtbuf  = (unsigned short*)ws; ws += (size_t)BB*H*DH*L*2;
  unsigned short* aobuf  = (unsigned short*)ws; ws += (size_t)BB*T*DIM*2;

  transpose_f32_bf16<<<dim3(3072/32, 1024/32), dim3(32,8), 0, stream>>>(wqkv, wqkvT, 1024, 3072);
  transpose_f32_bf16<<<dim3(1024/32, 1024/32), dim3(32,8), 0, stream>>>(wout, woutT, 1024, 1024);
  ln_kernel<<<dim3(8192), dim3(256), 0, stream>>>(x, ctx, lng, lnb, ln_all);
  qkv_gemm<<<dim3(1536), dim3(256), 0, stream>>>(ln_all, wqkvT, bqkv, qbuf, kbuf, vtbuf);
  attn_kernel<<<dim3(512), dim3(256), 0, stream>>>(qbuf, kbuf, vtbuf, aobuf);
  out_gemm<<<dim3(1024/128, 4096/128), dim3(256), 0, stream>>>(aobuf, woutT, bout, x, out);
}

// Round 6
// 222.387 us; speedup vs baseline: 1.8511x; 1.1270x over previous
//
#include <hip/hip_runtime.h>
#include <stdint.h>

#define H 16
#define DH 64
#define T 2048
#define SS 2048
#define L 4096
#define DIM 1024
#define BB 2

typedef __bf16 bf16x8 __attribute__((ext_vector_type(8)));
typedef float f32x4 __attribute__((ext_vector_type(4)));
typedef float f32x16 __attribute__((ext_vector_type(16)));
typedef unsigned u32x4 __attribute__((ext_vector_type(4)));

__device__ __forceinline__ unsigned short f2bf(float f){
  unsigned u = __builtin_bit_cast(unsigned, f);
  u += 0x7fff + ((u >> 16) & 1);
  return (unsigned short)(u >> 16);
}

__device__ __forceinline__ unsigned cvt_pk_bf16(float lo, float hi){
  unsigned r;
  asm("v_cvt_pk_bf16_f32 %0, %1, %2" : "=v"(r) : "v"(lo), "v"(hi));
  return r;
}

__device__ __forceinline__ float fmax3(float a, float b, float c){
  float r;
  asm("v_max3_f32 %0, %1, %2, %3" : "=v"(r) : "v"(a), "v"(b), "v"(c));
  return r;
}

__device__ __forceinline__ void gload_lds16(const void* g, void* l){
  void* gnc = const_cast<void*>(g);
  __builtin_amdgcn_global_load_lds((__attribute__((address_space(1))) void*)gnc,
                                   (__attribute__((address_space(3))) void*)l, 16, 0, 0);
}

// ---------------- LayerNorm (x rows then ctx rows) -> bf16 ----------------
__global__ __launch_bounds__(256) void ln_kernel(const float* __restrict__ x, const float* __restrict__ ctx,
                          const float* __restrict__ g, const float* __restrict__ b,
                          unsigned short* __restrict__ out){
  int row = blockIdx.x;
  int tid = threadIdx.x;
  const float* src = (row < BB*T) ? (x + (size_t)row*DIM) : (ctx + (size_t)(row - BB*T)*DIM);
  float4 v = reinterpret_cast<const float4*>(src)[tid];
  float s  = v.x + v.y + v.z + v.w;
  float s2 = v.x*v.x + v.y*v.y + v.z*v.z + v.w*v.w;
  #pragma unroll
  for (int off = 32; off > 0; off >>= 1){
    s  += __shfl_down(s,  off, 64);
    s2 += __shfl_down(s2, off, 64);
  }
  __shared__ float red[8];
  if ((tid & 63) == 0){ red[(tid>>6)*2] = s; red[(tid>>6)*2+1] = s2; }
  __syncthreads();
  s  = red[0] + red[2] + red[4] + red[6];
  s2 = red[1] + red[3] + red[5] + red[7];
  float mean = s * (1.0f/DIM);
  float var  = s2 * (1.0f/DIM) - mean*mean;
  float rstd = rsqrtf(var + 1e-5f);
  float4 gg = reinterpret_cast<const float4*>(g)[tid];
  float4 bv = reinterpret_cast<const float4*>(b)[tid];
  ushort4 o;
  o.x = f2bf((v.x-mean)*rstd*gg.x + bv.x);
  o.y = f2bf((v.y-mean)*rstd*gg.y + bv.y);
  o.z = f2bf((v.z-mean)*rstd*gg.z + bv.z);
  o.w = f2bf((v.w-mean)*rstd*gg.w + bv.w);
  reinterpret_cast<ushort4*>(out + (size_t)row*DIM)[tid] = o;
}

// ---------------- transpose fp32 [R][C] -> bf16 [C][R] ----------------
__global__ __launch_bounds__(256) void transpose_f32_bf16(const float* __restrict__ in,
                          unsigned short* __restrict__ out, int R, int C){
  __shared__ float tile[32][33];
  int c0 = blockIdx.x*32, r0 = blockIdx.y*32;
  int tx = threadIdx.x, ty = threadIdx.y;
  #pragma unroll
  for (int k = 0; k < 4; k++)
    tile[ty + k*8][tx] = in[(size_t)(r0 + ty + k*8)*C + c0 + tx];
  __syncthreads();
  #pragma unroll
  for (int k = 0; k < 4; k++)
    out[(size_t)(c0 + ty + k*8)*R + r0 + tx] = f2bf(tile[tx][ty + k*8]);
}

// ---------------- QKV GEMM: [8192 x 1024] @ [1024 x 3072], scatter epilogue ----------------
// Q is pre-scaled by (1/8)*log2(e) so attention softmax can run in exp2 domain.
__global__ __launch_bounds__(256) void qkv_gemm(const unsigned short* __restrict__ A,
      const unsigned short* __restrict__ Bt, const float* __restrict__ bias,
      unsigned short* __restrict__ qbuf, unsigned short* __restrict__ kbuf,
      unsigned short* __restrict__ vtbuf){
  // bijective XCD swizzle: 1536 blocks, 1536 % 8 == 0
  int orig = blockIdx.x;
  int wid = (orig & 7)*192 + (orig >> 3);
  int n0 = (wid % 24)*128, m0 = (wid / 24)*128;
  if (m0 >= BB*T && n0 < DIM) return;   // ctx rows need no Q columns
  __shared__ unsigned short at[128*32];
  __shared__ unsigned short btile[128*32];
  int tid = threadIdx.x, lane = tid & 63, wv = tid >> 6;
  int wm = (wv >> 1)*64, wn = (wv & 1)*64;
  f32x4 acc[4][4];
  #pragma unroll
  for (int i = 0; i < 4; i++)
    #pragma unroll
    for (int j = 0; j < 4; j++) acc[i][j] = (f32x4){0.f,0.f,0.f,0.f};

  for (int k0 = 0; k0 < DIM; k0 += 32){
    #pragma unroll
    for (int c = 0; c < 2; c++){
      int idx = c*256 + tid;
      int row = idx >> 2, koff = (idx & 3)*16;
      gload_lds16((const char*)A  + ((size_t)(m0+row)*DIM + k0)*2 + koff,
                  (char*)at + (c*256 + wv*64)*16);
      gload_lds16((const char*)Bt + ((size_t)(n0+row)*DIM + k0)*2 + koff,
                  (char*)btile + (c*256 + wv*64)*16);
    }
    __syncthreads();
    bf16x8 af[4], bfv[4];
    #pragma unroll
    for (int i = 0; i < 4; i++){
      af[i]  = *reinterpret_cast<const bf16x8*>((const char*)at    + (wm + i*16 + (lane&15))*64 + (lane>>4)*16);
      bfv[i] = *reinterpret_cast<const bf16x8*>((const char*)btile + (wn + i*16 + (lane&15))*64 + (lane>>4)*16);
    }
    #pragma unroll
    for (int mi = 0; mi < 4; mi++)
      #pragma unroll
      for (int ni = 0; ni < 4; ni++)
        acc[mi][ni] = __builtin_amdgcn_mfma_f32_16x16x32_bf16(af[mi], bfv[ni], acc[mi][ni], 0,0,0);
    __syncthreads();
  }

  #pragma unroll
  for (int ni = 0; ni < 4; ni++){
    int gn = n0 + wn + ni*16 + (lane & 15);
    float bv = bias[gn];
    int sec = gn >> 10, cc = gn & 1023, hh = cc >> 6, d = cc & 63;
    #pragma unroll
    for (int mi = 0; mi < 4; mi++){
      int gmb = m0 + wm + mi*16 + ((lane >> 4) << 2);
      bool isctx = gmb >= BB*T;
      int rm = isctx ? gmb - BB*T : gmb;
      int bidx = rm >> 11, tt = rm & 2047;
      size_t bh = (size_t)bidx*H + hh;
      if (sec == 0){
        if (isctx) continue;
        #pragma unroll
        for (int r = 0; r < 4; r++)
          qbuf[(bh*T + tt + r)*DH + d] = f2bf((acc[mi][ni][r] + bv)*0.18033688f); // 0.125*log2(e)
      } else if (sec == 1){
        int j = isctx ? T + tt : tt;
        #pragma unroll
        for (int r = 0; r < 4; r++)
          kbuf[(bh*L + j + r)*DH + d] = f2bf(acc[mi][ni][r] + bv);
      } else {
        int j = isctx ? T + tt : tt;
        ushort4 o;
        o.x = f2bf(acc[mi][ni][0] + bv);
        o.y = f2bf(acc[mi][ni][1] + bv);
        o.z = f2bf(acc[mi][ni][2] + bv);
        o.w = f2bf(acc[mi][ni][3] + bv);
        *reinterpret_cast<ushort4*>(vtbuf + (bh*DH + d)*L + j) = o;
      }
    }
  }
}

// ---------------- flash attention, split-KV x2: 32x32 MFMA, KVBLK=64, in-register P --------
// grid 1024 = 2 kv-chunks x 32 bh x 16 qt; 4 waves x 32 q = 128 q/block; LDS 32KB (dbuf)
// -> 4 blocks/CU, 16 waves/CU.  Each block covers kv [cb*2048, cb*2048+2048).
// Partials: normalized O (bf16) to obuf[cb], m/l (f32) to mbuf/lbuf; combined by attn_combine.
__global__ __launch_bounds__(256, 4) void attn_kernel(const unsigned short* __restrict__ q,
      const unsigned short* __restrict__ kbuf, const unsigned short* __restrict__ vtbuf,
      unsigned short* __restrict__ obuf, float* __restrict__ mbuf, float* __restrict__ lbuf){
  // XCD swizzle: each XCD gets 8 bh x 1 chunk x 16 qt (4MB of K/V -> fits its L2)
  int hw = blockIdx.x;
  int wid = (hw & 7)*128 + (hw >> 3);
  int qt = wid & 15, bh = (wid >> 4) & 31, cb = wid >> 9;
  int hh = bh & 15, b = bh >> 4;
  int tid = threadIdx.x, lane = tid & 63, wv = tid >> 6;  // 4 waves
  int hi = lane >> 5, q32 = lane & 31;
  __shared__ unsigned short kt[2][64*64];
  __shared__ unsigned short vtt[2][64*64];
  size_t bhs = (size_t)b*H + hh;
  int qbase = qt*128 + wv*32;

  // Q fragments (B-operand): lane holds q-col = q32, k = d = ks*16 + hi*8 + j
  const unsigned short* qp = q + (bhs*T + qbase + q32)*DH + hi*8;
  bf16x8 qf[4];
  #pragma unroll
  for (int ks = 0; ks < 4; ks++)
    qf[ks] = *reinterpret_cast<const bf16x8*>(qp + ks*16);

  bf16x8 ones;
  #pragma unroll
  for (int j = 0; j < 8; j++) ones[j] = (__bf16)1.0f;

  f32x16 o_acc[2], l_vec;
  #pragma unroll
  for (int d = 0; d < 2; d++)
    #pragma unroll
    for (int i = 0; i < 16; i++) o_acc[d][i] = 0.f;
  #pragma unroll
  for (int i = 0; i < 16; i++) l_vec[i] = 0.f;
  float m_l = -1e30f;

  const char* kg = (const char*)(kbuf + bhs*(size_t)L*DH) + (size_t)cb*2048*128;
  const char* vg = (const char*)(vtbuf + bhs*(size_t)DH*L) + (size_t)cb*4096;

  // stage one 64-kv tile (16KB): K [64 kv][64 d], V [64 d][64 kv], chunk-swizzled
  #define STAGE(bufi, jt) { \
    _Pragma("unroll") \
    for (int c = 0; c < 2; c++){ \
      int idx = c*256 + tid; \
      int row = idx >> 3, c16 = idx & 7; \
      int sc16 = c16 ^ (row & 7); \
      gload_lds16(kg + (size_t)((jt)*64 + row)*128 + sc16*16, \
                  (char*)kt[bufi] + (c*256 + wv*64)*16); \
      gload_lds16(vg + (size_t)row*(L*2) + (jt)*128 + sc16*16, \
                  (char*)vtt[bufi] + (c*256 + wv*64)*16); \
    } }

  STAGE(0, 0);
  __syncthreads();

  for (int jt = 0; jt < 32; ++jt){
    int bufi = jt & 1;
    if (jt + 1 < 32) STAGE(bufi^1, jt+1);   // prefetch overlaps compute
    const char* kb = (const char*)kt[bufi];
    const char* vb = (const char*)vtt[bufi];

    // S^T[kv][q]: two 32-kv blocks, chained over 4 k-steps of 16
    f32x16 sc[2];
    #pragma unroll
    for (int t = 0; t < 2; t++)
      #pragma unroll
      for (int i = 0; i < 16; i++) sc[t][i] = 0.f;
    #pragma unroll
    for (int ks = 0; ks < 4; ks++){
      #pragma unroll
      for (int t = 0; t < 2; t++){
        int row = t*32 + q32;
        bf16x8 kf = *reinterpret_cast<const bf16x8*>(kb + row*128 + (((ks*2+hi) ^ (row&7))*16));
        sc[t] = __builtin_amdgcn_mfma_f32_32x32x16_bf16(kf, qf[ks], sc[t], 0,0,0);
      }
    }

    // tile max via v_max3 tree
    float rt[2];
    #pragma unroll
    for (int t = 0; t < 2; t++){
      float v0 = fmax3(sc[t][0],  sc[t][1],  sc[t][2]);
      float v1 = fmax3(sc[t][3],  sc[t][4],  sc[t][5]);
      float v2 = fmax3(sc[t][6],  sc[t][7],  sc[t][8]);
      float v3 = fmax3(sc[t][9],  sc[t][10], sc[t][11]);
      float v4 = fmax3(sc[t][12], sc[t][13], sc[t][14]);
      rt[t] = fmaxf(fmax3(v0, v1, v2), fmax3(v3, v4, sc[t][15]));
    }
    float tm = fmaxf(rt[0], rt[1]);

    // online softmax (exp2 domain), defer-max THR=8
    if (!__all(tm - m_l <= 8.0f)){
      float tmf = fmaxf(tm, __shfl_xor(tm, 32, 64));
      float mn = fmaxf(m_l, tmf);
      float alpha = __builtin_amdgcn_exp2f(m_l - mn);
      m_l = mn;
      #pragma unroll
      for (int d = 0; d < 2; d++)
        #pragma unroll
        for (int i = 0; i < 16; i++) o_acc[d][i] *= alpha;
      l_vec[0] *= alpha;   // only reg 0 is ever read; MFMA adds equally to all regs
    }
    #pragma unroll
    for (int t = 0; t < 2; t++)
      #pragma unroll
      for (int i = 0; i < 16; i++)
        sc[t][i] = __builtin_amdgcn_exp2f(sc[t][i] - m_l);

    // P^T -> B-fragments, in-register: 16 cvt_pk + 8 permlane32_swap
    bf16x8 pfrag[4];
    #pragma unroll
    for (int t = 0; t < 2; t++){
      #pragma unroll
      for (int half = 0; half < 2; half++){
        unsigned p01 = cvt_pk_bf16(sc[t][half*8+0], sc[t][half*8+1]);
        unsigned p23 = cvt_pk_bf16(sc[t][half*8+2], sc[t][half*8+3]);
        unsigned p45 = cvt_pk_bf16(sc[t][half*8+4], sc[t][half*8+5]);
        unsigned p67 = cvt_pk_bf16(sc[t][half*8+6], sc[t][half*8+7]);
        asm("v_permlane32_swap_b32 %0, %1" : "+v"(p01), "+v"(p45));
        asm("v_permlane32_swap_b32 %0, %1" : "+v"(p23), "+v"(p67));
        u32x4 w = (u32x4){p01, p23, p45, p67};
        pfrag[t*2 + half] = __builtin_bit_cast(bf16x8, w);
      }
    }

    // O^T[d][q] += V^T @ P^T ; l_vec += ones @ P^T
    #pragma unroll
    for (int ks = 0; ks < 4; ks++){
      #pragma unroll
      for (int d = 0; d < 2; d++){
        int row = d*32 + q32;
        bf16x8 vf = *reinterpret_cast<const bf16x8*>(vb + row*128 + (((ks*2+hi) ^ (row&7))*16));
        o_acc[d] = __builtin_amdgcn_mfma_f32_32x32x16_bf16(vf, pfrag[ks], o_acc[d], 0,0,0);
      }
      l_vec = __builtin_amdgcn_mfma_f32_32x32x16_bf16(ones, pfrag[ks], l_vec, 0,0,0);
    }
    __syncthreads();   // drains prefetch vmcnt + protects kt/vtt reuse
  }

  // write normalized partial O (bf16) + m/l
  float inv = 1.0f / l_vec[0];
  unsigned short* aop = obuf + (size_t)cb*BB*H*T*DH + ((size_t)bh*T + qbase + q32)*DH;
  #pragma unroll
  for (int d = 0; d < 2; d++)
    #pragma unroll
    for (int rg = 0; rg < 4; rg++){
      int d0 = d*32 + rg*8 + hi*4;
      ushort4 o;
      o.x = __builtin_bit_cast(unsigned short, (__bf16)(o_acc[d][rg*4+0]*inv));
      o.y = __builtin_bit_cast(unsigned short, (__bf16)(o_acc[d][rg*4+1]*inv));
      o.z = __builtin_bit_cast(unsigned short, (__bf16)(o_acc[d][rg*4+2]*inv));
      o.w = __builtin_bit_cast(unsigned short, (__bf16)(o_acc[d][rg*4+3]*inv));
      *reinterpret_cast<ushort4*>(aop + d0) = o;
    }
  if (hi == 0){
    size_t mi = ((size_t)cb*BB*H + bh)*T + qbase + q32;
    mbuf[mi] = m_l;
    lbuf[mi] = l_vec[0];
  }
}

// ---------------- combine the two KV-chunk partials ----------------
__global__ __launch_bounds__(256) void attn_combine(const unsigned short* __restrict__ obuf,
      const float* __restrict__ mbuf, const float* __restrict__ lbuf,
      unsigned short* __restrict__ ao){
  int gid = blockIdx.x*256 + threadIdx.x;
  int d8 = gid & 7;
  int qg = gid >> 3;            // bh*T + q
  int qq = qg & (T-1);
  int bh = qg >> 11;
  int b = bh >> 4, h = bh & 15;
  float m0 = mbuf[(size_t)qg];
  float m1 = mbuf[(size_t)BB*H*T + qg];
  float l0 = lbuf[(size_t)qg];
  float l1 = lbuf[(size_t)BB*H*T + qg];
  float mm = fmaxf(m0, m1);
  float w0 = l0 * __builtin_amdgcn_exp2f(m0 - mm);
  float w1 = l1 * __builtin_amdgcn_exp2f(m1 - mm);
  float inv = 1.0f / (w0 + w1);
  w0 *= inv; w1 *= inv;
  bf16x8 o0 = *reinterpret_cast<const bf16x8*>(obuf + (size_t)qg*DH + d8*8);
  bf16x8 o1 = *reinterpret_cast<const bf16x8*>(obuf + (size_t)BB*H*T*DH + (size_t)qg*DH + d8*8);
  bf16x8 res;
  #pragma unroll
  for (int j = 0; j < 8; j++)
    res[j] = (__bf16)(w0*(float)o0[j] + w1*(float)o1[j]);
  *reinterpret_cast<bf16x8*>(ao + ((size_t)b*T + qq)*DIM + h*DH + d8*8) = res;
}

// ---------------- out projection + bias + residual (fp32 out) ----------------
__global__ __launch_bounds__(256) void out_gemm(const unsigned short* __restrict__ A,
      const unsigned short* __restrict__ Bt, const float* __restrict__ bout,
      const float* __restrict__ xres, float* __restrict__ out){
  int n0 = blockIdx.x*128, m0 = blockIdx.y*128;
  __shared__ unsigned short at[128*32];
  __shared__ unsigned short btile[128*32];
  int tid = threadIdx.x, lane = tid & 63, wv = tid >> 6;
  int wm = (wv >> 1)*64, wn = (wv & 1)*64;
  f32x4 acc[4][4];
  #pragma unroll
  for (int i = 0; i < 4; i++)
    #pragma unroll
    for (int j = 0; j < 4; j++) acc[i][j] = (f32x4){0.f,0.f,0.f,0.f};

  for (int k0 = 0; k0 < DIM; k0 += 32){
    #pragma unroll
    for (int c = 0; c < 2; c++){
      int idx = c*256 + tid;
      int row = idx >> 2, koff = (idx & 3)*16;
      gload_lds16((const char*)A  + ((size_t)(m0+row)*DIM + k0)*2 + koff,
                  (char*)at + (c*256 + wv*64)*16);
      gload_lds16((const char*)Bt + ((size_t)(n0+row)*DIM + k0)*2 + koff,
                  (char*)btile + (c*256 + wv*64)*16);
    }
    __syncthreads();
    bf16x8 af[4], bfv[4];
    #pragma unroll
    for (int i = 0; i < 4; i++){
      af[i]  = *reinterpret_cast<const bf16x8*>((const char*)at    + (wm + i*16 + (lane&15))*64 + (lane>>4)*16);
      bfv[i] = *reinterpret_cast<const bf16x8*>((const char*)btile + (wn + i*16 + (lane&15))*64 + (lane>>4)*16);
    }
    #pragma unroll
    for (int mi = 0; mi < 4; mi++)
      #pragma unroll
      for (int ni = 0; ni < 4; ni++)
        acc[mi][ni] = __builtin_amdgcn_mfma_f32_16x16x32_bf16(af[mi], bfv[ni], acc[mi][ni], 0,0,0);
    __syncthreads();
  }

  #pragma unroll
  for (int ni = 0; ni < 4; ni++){
    int gn = n0 + wn + ni*16 + (lane & 15);
    float bv = bout[gn];
    #pragma unroll
    for (int mi = 0; mi < 4; mi++){
      int gmb = m0 + wm + mi*16 + ((lane >> 4) << 2);
      #pragma unroll
      for (int r = 0; r < 4; r++){
        int gm = gmb + r;
        out[(size_t)gm*DIM + gn] = acc[mi][ni][r] + bv + xres[(size_t)gm*DIM + gn];
      }
    }
  }
}

extern "C" void kernel_launch(void* const* d_in, const int* in_sizes, int n_in,
                              void* d_out, int out_size, void* d_ws, size_t ws_size,
                              hipStream_t stream){
  const float* x    = (const float*)d_in[0];
  const float* ctx  = (const float*)d_in[1];
  const float* wqkv = (const float*)d_in[2];
  const float* bqkv = (const float*)d_in[3];
  const float* wout = (const float*)d_in[4];
  const float* bout = (const float*)d_in[5];
  const float* lng  = (const float*)d_in[6];
  const float* lnb  = (const float*)d_in[7];
  float* out = (float*)d_out;

  char* ws = (char*)d_ws;
  unsigned short* wqkvT  = (unsigned short*)ws; ws += (size_t)3072*1024*2;
  unsigned short* woutT  = (unsigned short*)ws; ws += (size_t)1024*1024*2;
  unsigned short* ln_all = (unsigned short*)ws; ws += (size_t)8192*1024*2;
  unsigned short* qbuf   = (unsigned short*)ws; ws += (size_t)BB*H*T*DH*2;
  unsigned short* kbuf   = (unsigned short*)ws; ws += (size_t)BB*H*L*DH*2;
  unsigned short* vtbuf  = (unsigned short*)ws; ws += (size_t)BB*H*DH*L*2;
  unsigned short* aobuf  = (unsigned short*)ws; ws += (size_t)BB*T*DIM*2;

  // dead-region reuse: obuf (2 x 8MB) = ln_all (16MB, dead after qkv_gemm);
  // mbuf/lbuf (0.5MB each) = wqkvT (6MB, dead after qkv_gemm)
  unsigned short* obuf = ln_all;
  float* mbuf = (float*)wqkvT;
  float* lbuf = mbuf + (size_t)2*BB*H*T;

  transpose_f32_bf16<<<dim3(3072/32, 1024/32), dim3(32,8), 0, stream>>>(wqkv, wqkvT, 1024, 3072);
  transpose_f32_bf16<<<dim3(1024/32, 1024/32), dim3(32,8), 0, stream>>>(wout, woutT, 1024, 1024);
  ln_kernel<<<dim3(8192), dim3(256), 0, stream>>>(x, ctx, lng, lnb, ln_all);
  qkv_gemm<<<dim3(1536), dim3(256), 0, stream>>>(ln_all, wqkvT, bqkv, qbuf, kbuf, vtbuf);
  attn_kernel<<<dim3(1024), dim3(256), 0, stream>>>(qbuf, kbuf, vtbuf, obuf, mbuf, lbuf);
  attn_combine<<<dim3(BB*H*T*8/256), dim3(256), 0, stream>>>(obuf, mbuf, lbuf, aobuf);
  out_gemm<<<dim3(1024/128, 4096/128), dim3(256), 0, stream>>>(aobuf, woutT, bout, x, out);
}

// Round 7
// 218.265 us; speedup vs baseline: 1.8861x; 1.0189x over previous
//
#include <hip/hip_runtime.h>
#include <stdint.h>

#define H 16
#define DH 64
#define T 2048
#define SS 2048
#define L 4096
#define DIM 1024
#define BB 2

typedef __bf16 bf16x8 __attribute__((ext_vector_type(8)));
typedef float f32x4 __attribute__((ext_vector_type(4)));
typedef float f32x16 __attribute__((ext_vector_type(16)));
typedef unsigned u32x4 __attribute__((ext_vector_type(4)));

__device__ __forceinline__ unsigned short f2bf(float f){
  unsigned u = __builtin_bit_cast(unsigned, f);
  u += 0x7fff + ((u >> 16) & 1);
  return (unsigned short)(u >> 16);
}

__device__ __forceinline__ unsigned cvt_pk_bf16(float lo, float hi){
  unsigned r;
  asm("v_cvt_pk_bf16_f32 %0, %1, %2" : "=v"(r) : "v"(lo), "v"(hi));
  return r;
}

__device__ __forceinline__ float fmax3(float a, float b, float c){
  float r;
  asm("v_max3_f32 %0, %1, %2, %3" : "=v"(r) : "v"(a), "v"(b), "v"(c));
  return r;
}

__device__ __forceinline__ void gload_lds16(const void* g, void* l){
  void* gnc = const_cast<void*>(g);
  __builtin_amdgcn_global_load_lds((__attribute__((address_space(1))) void*)gnc,
                                   (__attribute__((address_space(3))) void*)l, 16, 0, 0);
}

// ---------------- LayerNorm (x rows then ctx rows) -> bf16 ----------------
__global__ __launch_bounds__(256) void ln_kernel(const float* __restrict__ x, const float* __restrict__ ctx,
                          const float* __restrict__ g, const float* __restrict__ b,
                          unsigned short* __restrict__ out){
  int row = blockIdx.x;
  int tid = threadIdx.x;
  const float* src = (row < BB*T) ? (x + (size_t)row*DIM) : (ctx + (size_t)(row - BB*T)*DIM);
  float4 v = reinterpret_cast<const float4*>(src)[tid];
  float s  = v.x + v.y + v.z + v.w;
  float s2 = v.x*v.x + v.y*v.y + v.z*v.z + v.w*v.w;
  #pragma unroll
  for (int off = 32; off > 0; off >>= 1){
    s  += __shfl_down(s,  off, 64);
    s2 += __shfl_down(s2, off, 64);
  }
  __shared__ float red[8];
  if ((tid & 63) == 0){ red[(tid>>6)*2] = s; red[(tid>>6)*2+1] = s2; }
  __syncthreads();
  s  = red[0] + red[2] + red[4] + red[6];
  s2 = red[1] + red[3] + red[5] + red[7];
  float mean = s * (1.0f/DIM);
  float var  = s2 * (1.0f/DIM) - mean*mean;
  float rstd = rsqrtf(var + 1e-5f);
  float4 gg = reinterpret_cast<const float4*>(g)[tid];
  float4 bv = reinterpret_cast<const float4*>(b)[tid];
  ushort4 o;
  o.x = f2bf((v.x-mean)*rstd*gg.x + bv.x);
  o.y = f2bf((v.y-mean)*rstd*gg.y + bv.y);
  o.z = f2bf((v.z-mean)*rstd*gg.z + bv.z);
  o.w = f2bf((v.w-mean)*rstd*gg.w + bv.w);
  reinterpret_cast<ushort4*>(out + (size_t)row*DIM)[tid] = o;
}

// ---------------- transpose fp32 [R][C] -> bf16 [C][R] ----------------
__global__ __launch_bounds__(256) void transpose_f32_bf16(const float* __restrict__ in,
                          unsigned short* __restrict__ out, int R, int C){
  __shared__ float tile[32][33];
  int c0 = blockIdx.x*32, r0 = blockIdx.y*32;
  int tx = threadIdx.x, ty = threadIdx.y;
  #pragma unroll
  for (int k = 0; k < 4; k++)
    tile[ty + k*8][tx] = in[(size_t)(r0 + ty + k*8)*C + c0 + tx];
  __syncthreads();
  #pragma unroll
  for (int k = 0; k < 4; k++)
    out[(size_t)(c0 + ty + k*8)*R + r0 + tx] = f2bf(tile[tx][ty + k*8]);
}

// ---------------- QKV GEMM: [8192 x 1024] @ [1024 x 3072], LDS-staged coalesced epilogue ----
// n-tiles never straddle sections (1024 % 128 == 0): each block is pure Q, K, or V.
// Q is pre-scaled by (1/8)*log2(e) so attention softmax can run in exp2 domain.
__global__ __launch_bounds__(256) void qkv_gemm(const unsigned short* __restrict__ A,
      const unsigned short* __restrict__ Bt, const float* __restrict__ bias,
      unsigned short* __restrict__ qbuf, unsigned short* __restrict__ kbuf,
      unsigned short* __restrict__ vtbuf){
  // bijective XCD swizzle: 1536 blocks, 1536 % 8 == 0
  int orig = blockIdx.x;
  int wid = (orig & 7)*192 + (orig >> 3);
  int n0 = (wid % 24)*128, m0 = (wid / 24)*128;
  if (m0 >= BB*T && n0 < DIM) return;   // ctx rows need no Q columns
  __shared__ union {
    struct { unsigned short at[128*32]; unsigned short bt[128*32]; } s;
    unsigned short ct[128][136];   // [m][n] row-major (Q/K epilogue)
    unsigned short vt[128][136];   // [n][m] transposed (V epilogue)
  } u;
  int tid = threadIdx.x, lane = tid & 63, wv = tid >> 6;
  int wm = (wv >> 1)*64, wn = (wv & 1)*64;
  f32x4 acc[4][4];
  #pragma unroll
  for (int i = 0; i < 4; i++)
    #pragma unroll
    for (int j = 0; j < 4; j++) acc[i][j] = (f32x4){0.f,0.f,0.f,0.f};

  for (int k0 = 0; k0 < DIM; k0 += 32){
    #pragma unroll
    for (int c = 0; c < 2; c++){
      int idx = c*256 + tid;
      int row = idx >> 2, koff = (idx & 3)*16;
      gload_lds16((const char*)A  + ((size_t)(m0+row)*DIM + k0)*2 + koff,
                  (char*)u.s.at + (c*256 + wv*64)*16);
      gload_lds16((const char*)Bt + ((size_t)(n0+row)*DIM + k0)*2 + koff,
                  (char*)u.s.bt + (c*256 + wv*64)*16);
    }
    __syncthreads();
    bf16x8 af[4], bfv[4];
    #pragma unroll
    for (int i = 0; i < 4; i++){
      af[i]  = *reinterpret_cast<const bf16x8*>((const char*)u.s.at + (wm + i*16 + (lane&15))*64 + (lane>>4)*16);
      bfv[i] = *reinterpret_cast<const bf16x8*>((const char*)u.s.bt + (wn + i*16 + (lane&15))*64 + (lane>>4)*16);
    }
    #pragma unroll
    for (int mi = 0; mi < 4; mi++)
      #pragma unroll
      for (int ni = 0; ni < 4; ni++)
        acc[mi][ni] = __builtin_amdgcn_mfma_f32_16x16x32_bf16(af[mi], bfv[ni], acc[mi][ni], 0,0,0);
    __syncthreads();
  }

  int sec = n0 >> 10;   // 0=Q, 1=K, 2=V
  if (sec < 2){
    float scale = (sec == 0) ? 0.18033688f : 1.0f;  // 0.125*log2(e) for Q
    #pragma unroll
    for (int ni = 0; ni < 4; ni++){
      int nl = wn + ni*16 + (lane & 15);
      float bv = bias[n0 + nl];
      #pragma unroll
      for (int mi = 0; mi < 4; mi++){
        int ml = wm + mi*16 + ((lane >> 4) << 2);
        #pragma unroll
        for (int r = 0; r < 4; r++)
          u.ct[ml + r][nl] = f2bf((acc[mi][ni][r] + bv)*scale);
      }
    }
    __syncthreads();
    #pragma unroll
    for (int c = 0; c < 8; c++){
      int idx = c*256 + tid;
      int row = idx >> 4, ch = idx & 15;
      bf16x8 v = *reinterpret_cast<const bf16x8*>(&u.ct[row][ch*8]);
      int gm = m0 + row, gn = n0 + ch*8;
      int cc = gn & 1023, hh2 = cc >> 6, d = cc & 63;
      bool isctx = gm >= BB*T;
      int rm = isctx ? gm - BB*T : gm;
      int bidx = rm >> 11, tt = rm & 2047;
      size_t bh2 = (size_t)bidx*H + hh2;
      if (sec == 0){
        *reinterpret_cast<bf16x8*>(qbuf + (bh2*T + tt)*DH + d) = v;   // Q blocks are never ctx
      } else {
        int j = isctx ? T + tt : tt;
        *reinterpret_cast<bf16x8*>(kbuf + (bh2*L + j)*DH + d) = v;
      }
    }
  } else {
    #pragma unroll
    for (int ni = 0; ni < 4; ni++){
      int nl = wn + ni*16 + (lane & 15);
      float bv = bias[n0 + nl];
      #pragma unroll
      for (int mi = 0; mi < 4; mi++){
        int ml = wm + mi*16 + ((lane >> 4) << 2);
        ushort4 o;
        o.x = f2bf(acc[mi][ni][0] + bv);
        o.y = f2bf(acc[mi][ni][1] + bv);
        o.z = f2bf(acc[mi][ni][2] + bv);
        o.w = f2bf(acc[mi][ni][3] + bv);
        *reinterpret_cast<ushort4*>(&u.vt[nl][ml]) = o;   // 4 consecutive m at row n
      }
    }
    __syncthreads();
    #pragma unroll
    for (int c = 0; c < 8; c++){
      int idx = c*256 + tid;
      int nl = idx >> 4, ch = idx & 15;
      bf16x8 v = *reinterpret_cast<const bf16x8*>(&u.vt[nl][ch*8]);
      int gn = n0 + nl;
      int cc = gn & 1023, hh2 = cc >> 6, d = cc & 63;
      int gm = m0 + ch*8;
      bool isctx = gm >= BB*T;
      int rm = isctx ? gm - BB*T : gm;
      int bidx = rm >> 11, tt = rm & 2047;
      int j = isctx ? T + tt : tt;
      size_t bh2 = (size_t)bidx*H + hh2;
      *reinterpret_cast<bf16x8*>(vtbuf + (bh2*DH + d)*L + j) = v;
    }
  }
}

// ---------------- flash attention, split-KV x2: 32x32 MFMA, KVBLK=64, in-register P --------
// grid 1024 = 2 kv-chunks x 32 bh x 16 qt; 4 waves x 32 q = 128 q/block; LDS 32KB (dbuf)
// -> 4 blocks/CU, 16 waves/CU.  Each block covers kv [cb*2048, cb*2048+2048).
// Partials: normalized O (bf16) to obuf[cb], m/l (f32) to mbuf/lbuf; combined by attn_combine.
__global__ __launch_bounds__(256, 4) void attn_kernel(const unsigned short* __restrict__ q,
      const unsigned short* __restrict__ kbuf, const unsigned short* __restrict__ vtbuf,
      unsigned short* __restrict__ obuf, float* __restrict__ mbuf, float* __restrict__ lbuf){
  // XCD swizzle: each XCD gets 8 bh x 1 chunk x 16 qt (4MB of K/V -> fits its L2)
  int hw = blockIdx.x;
  int wid = (hw & 7)*128 + (hw >> 3);
  int qt = wid & 15, bh = (wid >> 4) & 31, cb = wid >> 9;
  int hh = bh & 15, b = bh >> 4;
  int tid = threadIdx.x, lane = tid & 63, wv = tid >> 6;  // 4 waves
  int hi = lane >> 5, q32 = lane & 31;
  __shared__ unsigned short kt[2][64*64];
  __shared__ unsigned short vtt[2][64*64];
  size_t bhs = (size_t)b*H + hh;
  int qbase = qt*128 + wv*32;

  // Q fragments (B-operand): lane holds q-col = q32, k = d = ks*16 + hi*8 + j
  const unsigned short* qp = q + (bhs*T + qbase + q32)*DH + hi*8;
  bf16x8 qf[4];
  #pragma unroll
  for (int ks = 0; ks < 4; ks++)
    qf[ks] = *reinterpret_cast<const bf16x8*>(qp + ks*16);

  bf16x8 ones;
  #pragma unroll
  for (int j = 0; j < 8; j++) ones[j] = (__bf16)1.0f;

  f32x16 o_acc[2], l_vec;
  #pragma unroll
  for (int d = 0; d < 2; d++)
    #pragma unroll
    for (int i = 0; i < 16; i++) o_acc[d][i] = 0.f;
  #pragma unroll
  for (int i = 0; i < 16; i++) l_vec[i] = 0.f;
  float m_l = -1e30f;

  const char* kg = (const char*)(kbuf + bhs*(size_t)L*DH) + (size_t)cb*2048*128;
  const char* vg = (const char*)(vtbuf + bhs*(size_t)DH*L) + (size_t)cb*4096;

  // stage one 64-kv tile (16KB): K [64 kv][64 d], V [64 d][64 kv], chunk-swizzled
  #define STAGE(bufi, jt) { \
    _Pragma("unroll") \
    for (int c = 0; c < 2; c++){ \
      int idx = c*256 + tid; \
      int row = idx >> 3, c16 = idx & 7; \
      int sc16 = c16 ^ (row & 7); \
      gload_lds16(kg + (size_t)((jt)*64 + row)*128 + sc16*16, \
                  (char*)kt[bufi] + (c*256 + wv*64)*16); \
      gload_lds16(vg + (size_t)row*(L*2) + (jt)*128 + sc16*16, \
                  (char*)vtt[bufi] + (c*256 + wv*64)*16); \
    } }

  STAGE(0, 0);
  __syncthreads();

  for (int jt = 0; jt < 32; ++jt){
    int bufi = jt & 1;
    if (jt + 1 < 32) STAGE(bufi^1, jt+1);   // prefetch overlaps compute
    const char* kb = (const char*)kt[bufi];
    const char* vb = (const char*)vtt[bufi];

    // S^T[kv][q]: two 32-kv blocks, chained over 4 k-steps of 16
    f32x16 sc[2];
    #pragma unroll
    for (int t = 0; t < 2; t++)
      #pragma unroll
      for (int i = 0; i < 16; i++) sc[t][i] = 0.f;
    #pragma unroll
    for (int ks = 0; ks < 4; ks++){
      #pragma unroll
      for (int t = 0; t < 2; t++){
        int row = t*32 + q32;
        bf16x8 kf = *reinterpret_cast<const bf16x8*>(kb + row*128 + (((ks*2+hi) ^ (row&7))*16));
        sc[t] = __builtin_amdgcn_mfma_f32_32x32x16_bf16(kf, qf[ks], sc[t], 0,0,0);
      }
    }

    // tile max via v_max3 tree
    float rt[2];
    #pragma unroll
    for (int t = 0; t < 2; t++){
      float v0 = fmax3(sc[t][0],  sc[t][1],  sc[t][2]);
      float v1 = fmax3(sc[t][3],  sc[t][4],  sc[t][5]);
      float v2 = fmax3(sc[t][6],  sc[t][7],  sc[t][8]);
      float v3 = fmax3(sc[t][9],  sc[t][10], sc[t][11]);
      float v4 = fmax3(sc[t][12], sc[t][13], sc[t][14]);
      rt[t] = fmaxf(fmax3(v0, v1, v2), fmax3(v3, v4, sc[t][15]));
    }
    float tm = fmaxf(rt[0], rt[1]);

    // online softmax (exp2 domain), defer-max THR=8
    if (!__all(tm - m_l <= 8.0f)){
      float tmf = fmaxf(tm, __shfl_xor(tm, 32, 64));
      float mn = fmaxf(m_l, tmf);
      float alpha = __builtin_amdgcn_exp2f(m_l - mn);
      m_l = mn;
      #pragma unroll
      for (int d = 0; d < 2; d++)
        #pragma unroll
        for (int i = 0; i < 16; i++) o_acc[d][i] *= alpha;
      l_vec[0] *= alpha;   // only reg 0 is ever read; MFMA adds equally to all regs
    }
    #pragma unroll
    for (int t = 0; t < 2; t++)
      #pragma unroll
      for (int i = 0; i < 16; i++)
        sc[t][i] = __builtin_amdgcn_exp2f(sc[t][i] - m_l);

    // P^T -> B-fragments, in-register: 16 cvt_pk + 8 permlane32_swap
    bf16x8 pfrag[4];
    #pragma unroll
    for (int t = 0; t < 2; t++){
      #pragma unroll
      for (int half = 0; half < 2; half++){
        unsigned p01 = cvt_pk_bf16(sc[t][half*8+0], sc[t][half*8+1]);
        unsigned p23 = cvt_pk_bf16(sc[t][half*8+2], sc[t][half*8+3]);
        unsigned p45 = cvt_pk_bf16(sc[t][half*8+4], sc[t][half*8+5]);
        unsigned p67 = cvt_pk_bf16(sc[t][half*8+6], sc[t][half*8+7]);
        asm("v_permlane32_swap_b32 %0, %1" : "+v"(p01), "+v"(p45));
        asm("v_permlane32_swap_b32 %0, %1" : "+v"(p23), "+v"(p67));
        u32x4 w = (u32x4){p01, p23, p45, p67};
        pfrag[t*2 + half] = __builtin_bit_cast(bf16x8, w);
      }
    }

    // O^T[d][q] += V^T @ P^T ; l_vec += ones @ P^T
    #pragma unroll
    for (int ks = 0; ks < 4; ks++){
      #pragma unroll
      for (int d = 0; d < 2; d++){
        int row = d*32 + q32;
        bf16x8 vf = *reinterpret_cast<const bf16x8*>(vb + row*128 + (((ks*2+hi) ^ (row&7))*16));
        o_acc[d] = __builtin_amdgcn_mfma_f32_32x32x16_bf16(vf, pfrag[ks], o_acc[d], 0,0,0);
      }
      l_vec = __builtin_amdgcn_mfma_f32_32x32x16_bf16(ones, pfrag[ks], l_vec, 0,0,0);
    }
    __syncthreads();   // drains prefetch vmcnt + protects kt/vtt reuse
  }

  // write normalized partial O (bf16) + m/l
  float inv = 1.0f / l_vec[0];
  unsigned short* aop = obuf + (size_t)cb*BB*H*T*DH + ((size_t)bh*T + qbase + q32)*DH;
  #pragma unroll
  for (int d = 0; d < 2; d++)
    #pragma unroll
    for (int rg = 0; rg < 4; rg++){
      int d0 = d*32 + rg*8 + hi*4;
      ushort4 o;
      o.x = __builtin_bit_cast(unsigned short, (__bf16)(o_acc[d][rg*4+0]*inv));
      o.y = __builtin_bit_cast(unsigned short, (__bf16)(o_acc[d][rg*4+1]*inv));
      o.z = __builtin_bit_cast(unsigned short, (__bf16)(o_acc[d][rg*4+2]*inv));
      o.w = __builtin_bit_cast(unsigned short, (__bf16)(o_acc[d][rg*4+3]*inv));
      *reinterpret_cast<ushort4*>(aop + d0) = o;
    }
  if (hi == 0){
    size_t mi = ((size_t)cb*BB*H + bh)*T + qbase + q32;
    mbuf[mi] = m_l;
    lbuf[mi] = l_vec[0];
  }
}

// ---------------- combine the two KV-chunk partials ----------------
__global__ __launch_bounds__(256) void attn_combine(const unsigned short* __restrict__ obuf,
      const float* __restrict__ mbuf, const float* __restrict__ lbuf,
      unsigned short* __restrict__ ao){
  int gid = blockIdx.x*256 + threadIdx.x;
  int d8 = gid & 7;
  int qg = gid >> 3;            // bh*T + q
  int qq = qg & (T-1);
  int bh = qg >> 11;
  int b = bh >> 4, h = bh & 15;
  float m0 = mbuf[(size_t)qg];
  float m1 = mbuf[(size_t)BB*H*T + qg];
  float l0 = lbuf[(size_t)qg];
  float l1 = lbuf[(size_t)BB*H*T + qg];
  float mm = fmaxf(m0, m1);
  float w0 = l0 * __builtin_amdgcn_exp2f(m0 - mm);
  float w1 = l1 * __builtin_amdgcn_exp2f(m1 - mm);
  float inv = 1.0f / (w0 + w1);
  w0 *= inv; w1 *= inv;
  bf16x8 o0 = *reinterpret_cast<const bf16x8*>(obuf + (size_t)qg*DH + d8*8);
  bf16x8 o1 = *reinterpret_cast<const bf16x8*>(obuf + (size_t)BB*H*T*DH + (size_t)qg*DH + d8*8);
  bf16x8 res;
  #pragma unroll
  for (int j = 0; j < 8; j++)
    res[j] = (__bf16)(w0*(float)o0[j] + w1*(float)o1[j]);
  *reinterpret_cast<bf16x8*>(ao + ((size_t)b*T + qq)*DIM + h*DH + d8*8) = res;
}

// ---------------- out projection + bias + residual (fp32 out) ----------------
__global__ __launch_bounds__(256) void out_gemm(const unsigned short* __restrict__ A,
      const unsigned short* __restrict__ Bt, const float* __restrict__ bout,
      const float* __restrict__ xres, float* __restrict__ out){
  int n0 = blockIdx.x*128, m0 = blockIdx.y*128;
  __shared__ unsigned short at[128*32];
  __shared__ unsigned short btile[128*32];
  int tid = threadIdx.x, lane = tid & 63, wv = tid >> 6;
  int wm = (wv >> 1)*64, wn = (wv & 1)*64;
  f32x4 acc[4][4];
  #pragma unroll
  for (int i = 0; i < 4; i++)
    #pragma unroll
    for (int j = 0; j < 4; j++) acc[i][j] = (f32x4){0.f,0.f,0.f,0.f};

  for (int k0 = 0; k0 < DIM; k0 += 32){
    #pragma unroll
    for (int c = 0; c < 2; c++){
      int idx = c*256 + tid;
      int row = idx >> 2, koff = (idx & 3)*16;
      gload_lds16((const char*)A  + ((size_t)(m0+row)*DIM + k0)*2 + koff,
                  (char*)at + (c*256 + wv*64)*16);
      gload_lds16((const char*)Bt + ((size_t)(n0+row)*DIM + k0)*2 + koff,
                  (char*)btile + (c*256 + wv*64)*16);
    }
    __syncthreads();
    bf16x8 af[4], bfv[4];
    #pragma unroll
    for (int i = 0; i < 4; i++){
      af[i]  = *reinterpret_cast<const bf16x8*>((const char*)at    + (wm + i*16 + (lane&15))*64 + (lane>>4)*16);
      bfv[i] = *reinterpret_cast<const bf16x8*>((const char*)btile + (wn + i*16 + (lane&15))*64 + (lane>>4)*16);
    }
    #pragma unroll
    for (int mi = 0; mi < 4; mi++)
      #pragma unroll
      for (int ni = 0; ni < 4; ni++)
        acc[mi][ni] = __builtin_amdgcn_mfma_f32_16x16x32_bf16(af[mi], bfv[ni], acc[mi][ni], 0,0,0);
    __syncthreads();
  }

  #pragma unroll
  for (int ni = 0; ni < 4; ni++){
    int gn = n0 + wn + ni*16 + (lane & 15);
    float bv = bout[gn];
    #pragma unroll
    for (int mi = 0; mi < 4; mi++){
      int gmb = m0 + wm + mi*16 + ((lane >> 4) << 2);
      #pragma unroll
      for (int r = 0; r < 4; r++){
        int gm = gmb + r;
        out[(size_t)gm*DIM + gn] = acc[mi][ni][r] + bv + xres[(size_t)gm*DIM + gn];
      }
    }
  }
}

extern "C" void kernel_launch(void* const* d_in, const int* in_sizes, int n_in,
                              void* d_out, int out_size, void* d_ws, size_t ws_size,
                              hipStream_t stream){
  const float* x    = (const float*)d_in[0];
  const float* ctx  = (const float*)d_in[1];
  const float* wqkv = (const float*)d_in[2];
  const float* bqkv = (const float*)d_in[3];
  const float* wout = (const float*)d_in[4];
  const float* bout = (const float*)d_in[5];
  const float* lng  = (const float*)d_in[6];
  const float* lnb  = (const float*)d_in[7];
  float* out = (float*)d_out;

  char* ws = (char*)d_ws;
  unsigned short* wqkvT  = (unsigned short*)ws; ws += (size_t)3072*1024*2;
  unsigned short* woutT  = (unsigned short*)ws; ws += (size_t)1024*1024*2;
  unsigned short* ln_all = (unsigned short*)ws; ws += (size_t)8192*1024*2;
  unsigned short* qbuf   = (unsigned short*)ws; ws += (size_t)BB*H*T*DH*2;
  unsigned short* kbuf   = (unsigned short*)ws; ws += (size_t)BB*H*L*DH*2;
  unsigned short* vtbuf  = (unsigned short*)ws; ws += (size_t)BB*H*DH*L*2;
  unsigned short* aobuf  = (unsigned short*)ws; ws += (size_t)BB*T*DIM*2;

  // dead-region reuse: obuf (2 x 8MB) = ln_all (16MB, dead after qkv_gemm);
  // mbuf/lbuf (0.5MB each) = wqkvT (6MB, dead after qkv_gemm)
  unsigned short* obuf = ln_all;
  float* mbuf = (float*)wqkvT;
  float* lbuf = mbuf + (size_t)2*BB*H*T;

  transpose_f32_bf16<<<dim3(3072/32, 1024/32), dim3(32,8), 0, stream>>>(wqkv, wqkvT, 1024, 3072);
  transpose_f32_bf16<<<dim3(1024/32, 1024/32), dim3(32,8), 0, stream>>>(wout, woutT, 1024, 1024);
  ln_kernel<<<dim3(8192), dim3(256), 0, stream>>>(x, ctx, lng, lnb, ln_all);
  qkv_gemm<<<dim3(1536), dim3(256), 0, stream>>>(ln_all, wqkvT, bqkv, qbuf, kbuf, vtbuf);
  attn_kernel<<<dim3(1024), dim3(256), 0, stream>>>(qbuf, kbuf, vtbuf, obuf, mbuf, lbuf);
  attn_combine<<<dim3(BB*H*T*8/256), dim3(256), 0, stream>>>(obuf, mbuf, lbuf, aobuf);
  out_gemm<<<dim3(1024/128, 4096/128), dim3(256), 0, stream>>>(aobuf, woutT, bout, x, out);
}